// Round 1
// baseline (2532.042 us; speedup 1.0000x reference)
//
#include <hip/hip_runtime.h>

#define NN   100000
#define EE   3200000
#define DIN  83
#define DHID 1024
#define NCLS 25

static __device__ __forceinline__ float relu_(float v) { return v > 0.f ? v : 0.f; }

// K1: Conv1d(1->4,k5,p2) + channel-sum + bias + relu, collapsed to a 5-tap conv
__global__ void conv_relu_k(const float* __restrict__ feature,
                            const float* __restrict__ conv_w,
                            const float* __restrict__ conv_b,
                            float* __restrict__ x) {
  float ws0 = conv_w[0] + conv_w[5] + conv_w[10] + conv_w[15];
  float ws1 = conv_w[1] + conv_w[6] + conv_w[11] + conv_w[16];
  float ws2 = conv_w[2] + conv_w[7] + conv_w[12] + conv_w[17];
  float ws3 = conv_w[3] + conv_w[8] + conv_w[13] + conv_w[18];
  float ws4 = conv_w[4] + conv_w[9] + conv_w[14] + conv_w[19];
  float bs  = conv_b[0] + conv_b[1] + conv_b[2] + conv_b[3];
  const int total = NN * DIN;
  for (int idx = blockIdx.x * blockDim.x + threadIdx.x; idx < total;
       idx += gridDim.x * blockDim.x) {
    int n = idx / DIN;
    int i = idx - n * DIN;
    const float* f = feature + n * DIN;
    float acc = bs;
    if (i >= 2)      acc += ws0 * f[i - 2];
    if (i >= 1)      acc += ws1 * f[i - 1];
    acc += ws2 * f[i];
    if (i + 1 < DIN) acc += ws3 * f[i + 1];
    if (i + 2 < DIN) acc += ws4 * f[i + 2];
    x[idx] = relu_(acc);
  }
}

__global__ void zero_k(float* __restrict__ p, int total) {
  for (int i = blockIdx.x * blockDim.x + threadIdx.x; i < total;
       i += gridDim.x * blockDim.x)
    p[i] = 0.f;
}

// out[idx] = b2[idx % 25]
__global__ void initout_k(const float* __restrict__ b2, float* __restrict__ out) {
  const int total = NN * NCLS;
  for (int idx = blockIdx.x * blockDim.x + threadIdx.x; idx < total;
       idx += gridDim.x * blockDim.x) {
    int q = idx % NCLS;
    out[idx] = b2[q];
  }
}

// SpMM: dst[row[e], i] += vals[e] * src[col[e], i], flat edge×dim parallel, f32 atomics
template <int D>
__global__ void spmm_k(const float* __restrict__ vals,
                       const int* __restrict__ row,
                       const int* __restrict__ col,
                       const float* __restrict__ src,
                       float* __restrict__ dst) {
  const long long total = (long long)EE * D;
  const long long stride = (long long)gridDim.x * blockDim.x;
  for (long long t = (long long)blockIdx.x * blockDim.x + threadIdx.x; t < total;
       t += stride) {
    int e = (int)(t / D);
    int i = (int)(t - (long long)e * D);
    float v = vals[e];
    int r = row[e];
    int c = col[e];
    atomicAdd(dst + r * D + i, v * src[c * D + i]);
  }
}

// Fused MLP: z = relu(ax @ W1 + b1) @ W2, never materializing h in global.
// Block = 256 threads, 64 nodes. Hidden chunked by 128 through LDS.
__global__ __launch_bounds__(256) void fused_mlp_k(
    const float* __restrict__ ax, const float* __restrict__ W1,
    const float* __restrict__ b1, const float* __restrict__ W2,
    float* __restrict__ z) {
  __shared__ float axs[64][84];   // +1 pad
  __shared__ float hs[64][132];   // 128 + 4 pad (keeps 16B alignment, 2-way banks)
  const int tid = threadIdx.x;
  const int n0 = blockIdx.x * 64;

  for (int idx = tid; idx < 64 * DIN; idx += 256) {
    int r = idx / DIN;
    int ci = idx - r * DIN;
    int n = n0 + r;
    axs[r][ci] = (n < NN) ? ax[n * DIN + ci] : 0.f;
  }
  __syncthreads();

  const int tx = tid & 31;   // 32 col-quads of the 128-chunk
  const int ty = tid >> 5;   // 8 node-groups of 8
  const int zn = tid >> 2;   // phase-2: node 0..63
  const int ql = tid & 3;    // phase-2: class lane

  float zacc[7];
#pragma unroll
  for (int m = 0; m < 7; ++m) zacc[m] = 0.f;

  for (int c = 0; c < DHID / 128; ++c) {
    const int j0 = c * 128 + tx * 4;
    float acc[8][4];
#pragma unroll
    for (int nn = 0; nn < 8; ++nn) {
      acc[nn][0] = 0.f; acc[nn][1] = 0.f; acc[nn][2] = 0.f; acc[nn][3] = 0.f;
    }
    // phase 1: H-chunk [64,128] = axs[64,83] @ W1[83,128-chunk]
    int k = 0;
    for (; k < 80; k += 4) {
      float4 w0 = *(const float4*)&W1[(k + 0) * DHID + j0];
      float4 w1 = *(const float4*)&W1[(k + 1) * DHID + j0];
      float4 w2 = *(const float4*)&W1[(k + 2) * DHID + j0];
      float4 w3 = *(const float4*)&W1[(k + 3) * DHID + j0];
#pragma unroll
      for (int nn = 0; nn < 8; ++nn) {
        float4 a4 = *(const float4*)&axs[ty * 8 + nn][k];
        acc[nn][0] += a4.x * w0.x + a4.y * w1.x + a4.z * w2.x + a4.w * w3.x;
        acc[nn][1] += a4.x * w0.y + a4.y * w1.y + a4.z * w2.y + a4.w * w3.y;
        acc[nn][2] += a4.x * w0.z + a4.y * w1.z + a4.z * w2.z + a4.w * w3.z;
        acc[nn][3] += a4.x * w0.w + a4.y * w1.w + a4.z * w2.w + a4.w * w3.w;
      }
    }
    for (; k < DIN; ++k) {  // k = 80..82
      float4 w0 = *(const float4*)&W1[k * DHID + j0];
#pragma unroll
      for (int nn = 0; nn < 8; ++nn) {
        float a = axs[ty * 8 + nn][k];
        acc[nn][0] += a * w0.x;
        acc[nn][1] += a * w0.y;
        acc[nn][2] += a * w0.z;
        acc[nn][3] += a * w0.w;
      }
    }
    float4 bb = *(const float4*)&b1[j0];
#pragma unroll
    for (int nn = 0; nn < 8; ++nn) {
      float4 hv;
      hv.x = relu_(acc[nn][0] + bb.x);
      hv.y = relu_(acc[nn][1] + bb.y);
      hv.z = relu_(acc[nn][2] + bb.z);
      hv.w = relu_(acc[nn][3] + bb.w);
      *(float4*)&hs[ty * 8 + nn][tx * 4] = hv;
    }
    __syncthreads();

    // phase 2: z[64,25] += H-chunk[64,128] @ W2[chunk,25]; thread owns (node, q%4 set)
    const float* W2c = W2 + c * 128 * NCLS;
    for (int j = 0; j < 128; j += 4) {
      float4 h4 = *(const float4*)&hs[zn][j];
      const float* w2r = W2c + j * NCLS + ql;
#pragma unroll
      for (int m = 0; m < 7; ++m) {
        int q = ql + 4 * m;
        if (q < NCLS) {
          zacc[m] += h4.x * w2r[0 * NCLS + 4 * m]
                   + h4.y * w2r[1 * NCLS + 4 * m]
                   + h4.z * w2r[2 * NCLS + 4 * m]
                   + h4.w * w2r[3 * NCLS + 4 * m];
        }
      }
    }
    __syncthreads();
  }

  const int n = n0 + zn;
  if (n < NN) {
#pragma unroll
    for (int m = 0; m < 7; ++m) {
      int q = ql + 4 * m;
      if (q < NCLS) z[n * NCLS + q] = zacc[m];
    }
  }
}

extern "C" void kernel_launch(void* const* d_in, const int* in_sizes, int n_in,
                              void* d_out, int out_size, void* d_ws, size_t ws_size,
                              hipStream_t stream) {
  const float* feature = (const float*)d_in[0];
  const float* conv_w  = (const float*)d_in[1];
  const float* conv_b  = (const float*)d_in[2];
  const float* W1      = (const float*)d_in[3];
  const float* b1      = (const float*)d_in[4];
  const float* W2      = (const float*)d_in[5];
  const float* b2      = (const float*)d_in[6];
  const float* adj     = (const float*)d_in[7];
  const int*   erow    = (const int*)d_in[8];
  const int*   ecol    = (const int*)d_in[9];
  float* out = (float*)d_out;

  float* x  = (float*)d_ws;                       // [NN, 83]
  float* ax = x  + (size_t)NN * DIN;              // [NN, 83]
  float* z  = ax + (size_t)NN * DIN;              // [NN, 25]

  // 1) x = relu(conv_sum(feature))
  conv_relu_k<<<8192, 256, 0, stream>>>(feature, conv_w, conv_b, x);
  // 2) ax = 0; ax += A @ x   (SpMM over 83 dims)
  zero_k<<<8192, 256, 0, stream>>>(ax, NN * DIN);
  spmm_k<DIN><<<32768, 256, 0, stream>>>(adj, erow, ecol, x, ax);
  // 3) z = relu(ax @ W1 + b1) @ W2  (fused, h never materialized)
  fused_mlp_k<<<(NN + 63) / 64, 256, 0, stream>>>(ax, W1, b1, W2, z);
  // 4) out = b2; out += A @ z  (SpMM over 25 dims)
  initout_k<<<4096, 256, 0, stream>>>(b2, out);
  spmm_k<NCLS><<<16384, 256, 0, stream>>>(adj, erow, ecol, z, out);
}

// Round 2
// 1712.116 us; speedup vs baseline: 1.4789x; 1.4789x over previous
//
#include <hip/hip_runtime.h>

#define NN   100000
#define EE   3200000
#define DIN  83
#define DHID 1024
#define NCLS 25

#define NB_PART 391   // ceil(NN/256)

static __device__ __forceinline__ float relu_(float v) { return v > 0.f ? v : 0.f; }

// K1: Conv1d(1->4,k5,p2) + channel-sum + bias + relu, collapsed to a 5-tap conv
__global__ void conv_relu_k(const float* __restrict__ feature,
                            const float* __restrict__ conv_w,
                            const float* __restrict__ conv_b,
                            float* __restrict__ x) {
  float ws0 = conv_w[0] + conv_w[5] + conv_w[10] + conv_w[15];
  float ws1 = conv_w[1] + conv_w[6] + conv_w[11] + conv_w[16];
  float ws2 = conv_w[2] + conv_w[7] + conv_w[12] + conv_w[17];
  float ws3 = conv_w[3] + conv_w[8] + conv_w[13] + conv_w[18];
  float ws4 = conv_w[4] + conv_w[9] + conv_w[14] + conv_w[19];
  float bs  = conv_b[0] + conv_b[1] + conv_b[2] + conv_b[3];
  const int total = NN * DIN;
  for (int idx = blockIdx.x * blockDim.x + threadIdx.x; idx < total;
       idx += gridDim.x * blockDim.x) {
    int n = idx / DIN;
    int i = idx - n * DIN;
    const float* f = feature + n * DIN;
    float acc = bs;
    if (i >= 2)      acc += ws0 * f[i - 2];
    if (i >= 1)      acc += ws1 * f[i - 1];
    acc += ws2 * f[i];
    if (i + 1 < DIN) acc += ws3 * f[i + 1];
    if (i + 2 < DIN) acc += ws4 * f[i + 2];
    x[idx] = relu_(acc);
  }
}

__global__ void zero_int_k(int* __restrict__ p, int total) {
  for (int i = blockIdx.x * blockDim.x + threadIdx.x; i < total;
       i += gridDim.x * blockDim.x)
    p[i] = 0;
}

// ---- CSR build ----
__global__ void hist_k(const int* __restrict__ row, int* __restrict__ counts) {
  for (int e = blockIdx.x * blockDim.x + threadIdx.x; e < EE;
       e += gridDim.x * blockDim.x)
    atomicAdd(&counts[row[e]], 1);
}

// per-block sums of counts
__global__ void partial_k(const int* __restrict__ counts, int* __restrict__ partial) {
  __shared__ int sd[256];
  int t = threadIdx.x;
  int i = blockIdx.x * 256 + t;
  sd[t] = (i < NN) ? counts[i] : 0;
  __syncthreads();
  for (int off = 128; off > 0; off >>= 1) {
    if (t < off) sd[t] += sd[t + off];
    __syncthreads();
  }
  if (t == 0) partial[blockIdx.x] = sd[0];
}

// single-block exclusive scan of 391 partials (Hillis-Steele over 512)
__global__ void scanpart_k(const int* __restrict__ partial, int* __restrict__ base) {
  __shared__ int sd[512];
  int t = threadIdx.x;
  int v = (t < NB_PART) ? partial[t] : 0;
  sd[t] = v;
  __syncthreads();
  for (int off = 1; off < 512; off <<= 1) {
    int add = (t >= off) ? sd[t - off] : 0;
    __syncthreads();
    sd[t] += add;
    __syncthreads();
  }
  if (t < NB_PART) base[t] = sd[t] - v;  // exclusive
}

// per-block exclusive scan + base -> offsets, cursor
__global__ void offsets_k(const int* __restrict__ counts, const int* __restrict__ base,
                          int* __restrict__ offs, int* __restrict__ cursor) {
  __shared__ int sd[256];
  int t = threadIdx.x;
  int i = blockIdx.x * 256 + t;
  int v = (i < NN) ? counts[i] : 0;
  sd[t] = v;
  __syncthreads();
  for (int off = 1; off < 256; off <<= 1) {
    int add = (t >= off) ? sd[t - off] : 0;
    __syncthreads();
    sd[t] += add;
    __syncthreads();
  }
  if (i < NN) {
    int excl = sd[t] - v + base[blockIdx.x];
    offs[i] = excl;
    cursor[i] = excl;
  }
}

// scatter edges into row-sorted (col, val) pairs
__global__ void scatter_k(const float* __restrict__ vals, const int* __restrict__ row,
                          const int* __restrict__ col, int* __restrict__ cursor,
                          int2* __restrict__ csr) {
  for (int e = blockIdx.x * blockDim.x + threadIdx.x; e < EE;
       e += gridDim.x * blockDim.x) {
    int r = row[e];
    int pos = atomicAdd(&cursor[r], 1);
    csr[pos] = make_int2(col[e], __float_as_int(vals[e]));
  }
}

// ---- gather SpMM, D=83: one wave per row, lanes = dims ----
__global__ __launch_bounds__(256) void spmm83_g(
    const int* __restrict__ offs, const int* __restrict__ cnt,
    const int2* __restrict__ csr, const float* __restrict__ x,
    float* __restrict__ ax) {
  int wave = (int)((blockIdx.x * blockDim.x + threadIdx.x) >> 6);
  int lane = threadIdx.x & 63;
  if (wave >= NN) return;
  int s = offs[wave];
  int n = cnt[wave];
  bool hi = lane < (DIN - 64);  // 19 lanes carry dims 64..82
  float a0 = 0.f, a1 = 0.f;
  for (int i = 0; i < n; ++i) {
    int2 p = csr[s + i];               // broadcast (same addr across wave)
    float v = __int_as_float(p.y);
    const float* xr = x + (size_t)p.x * DIN;
    a0 += v * xr[lane];
    if (hi) a1 += v * xr[64 + lane];
  }
  float* dr = ax + (size_t)wave * DIN;
  dr[lane] = a0;
  if (hi) dr[64 + lane] = a1;
}

// ---- gather SpMM, D=25: two rows per wave (half-wave each), +b2 fused ----
__global__ __launch_bounds__(256) void spmm25_g(
    const int* __restrict__ offs, const int* __restrict__ cnt,
    const int2* __restrict__ csr, const float* __restrict__ z,
    const float* __restrict__ b2, float* __restrict__ out) {
  int gw = (int)((blockIdx.x * blockDim.x + threadIdx.x) >> 6);
  int lane = threadIdx.x & 63;
  int half = lane >> 5;
  int d = lane & 31;
  int r = gw * 2 + half;
  if (r >= NN || d >= NCLS) return;
  int s = offs[r];
  int n = cnt[r];
  float acc = 0.f;
  for (int i = 0; i < n; ++i) {
    int2 p = csr[s + i];               // broadcast within half-wave
    acc += __int_as_float(p.y) * z[(size_t)p.x * NCLS + d];
  }
  out[(size_t)r * NCLS + d] = acc + b2[d];
}

// Fused MLP: z = relu(ax @ W1 + b1) @ W2, h never in global.
__global__ __launch_bounds__(256) void fused_mlp_k(
    const float* __restrict__ ax, const float* __restrict__ W1,
    const float* __restrict__ b1, const float* __restrict__ W2,
    float* __restrict__ z) {
  __shared__ float axs[64][84];   // +1 pad
  __shared__ float hs[64][132];   // 128 + 4 pad
  const int tid = threadIdx.x;
  const int n0 = blockIdx.x * 64;

  for (int idx = tid; idx < 64 * DIN; idx += 256) {
    int r = idx / DIN;
    int ci = idx - r * DIN;
    int n = n0 + r;
    axs[r][ci] = (n < NN) ? ax[n * DIN + ci] : 0.f;
  }
  __syncthreads();

  const int tx = tid & 31;
  const int ty = tid >> 5;
  const int zn = tid >> 2;
  const int ql = tid & 3;

  float zacc[7];
#pragma unroll
  for (int m = 0; m < 7; ++m) zacc[m] = 0.f;

  for (int c = 0; c < DHID / 128; ++c) {
    const int j0 = c * 128 + tx * 4;
    float acc[8][4];
#pragma unroll
    for (int nn = 0; nn < 8; ++nn) {
      acc[nn][0] = 0.f; acc[nn][1] = 0.f; acc[nn][2] = 0.f; acc[nn][3] = 0.f;
    }
    int k = 0;
    for (; k < 80; k += 4) {
      float4 w0 = *(const float4*)&W1[(k + 0) * DHID + j0];
      float4 w1 = *(const float4*)&W1[(k + 1) * DHID + j0];
      float4 w2 = *(const float4*)&W1[(k + 2) * DHID + j0];
      float4 w3 = *(const float4*)&W1[(k + 3) * DHID + j0];
#pragma unroll
      for (int nn = 0; nn < 8; ++nn) {
        float4 a4 = *(const float4*)&axs[ty * 8 + nn][k];
        acc[nn][0] += a4.x * w0.x + a4.y * w1.x + a4.z * w2.x + a4.w * w3.x;
        acc[nn][1] += a4.x * w0.y + a4.y * w1.y + a4.z * w2.y + a4.w * w3.y;
        acc[nn][2] += a4.x * w0.z + a4.y * w1.z + a4.z * w2.z + a4.w * w3.z;
        acc[nn][3] += a4.x * w0.w + a4.y * w1.w + a4.z * w2.w + a4.w * w3.w;
      }
    }
    for (; k < DIN; ++k) {
      float4 w0 = *(const float4*)&W1[k * DHID + j0];
#pragma unroll
      for (int nn = 0; nn < 8; ++nn) {
        float a = axs[ty * 8 + nn][k];
        acc[nn][0] += a * w0.x;
        acc[nn][1] += a * w0.y;
        acc[nn][2] += a * w0.z;
        acc[nn][3] += a * w0.w;
      }
    }
    float4 bb = *(const float4*)&b1[j0];
#pragma unroll
    for (int nn = 0; nn < 8; ++nn) {
      float4 hv;
      hv.x = relu_(acc[nn][0] + bb.x);
      hv.y = relu_(acc[nn][1] + bb.y);
      hv.z = relu_(acc[nn][2] + bb.z);
      hv.w = relu_(acc[nn][3] + bb.w);
      *(float4*)&hs[ty * 8 + nn][tx * 4] = hv;
    }
    __syncthreads();

    const float* W2c = W2 + c * 128 * NCLS;
    for (int j = 0; j < 128; j += 4) {
      float4 h4 = *(const float4*)&hs[zn][j];
      const float* w2r = W2c + j * NCLS + ql;
#pragma unroll
      for (int m = 0; m < 7; ++m) {
        int q = ql + 4 * m;
        if (q < NCLS) {
          zacc[m] += h4.x * w2r[0 * NCLS + 4 * m]
                   + h4.y * w2r[1 * NCLS + 4 * m]
                   + h4.z * w2r[2 * NCLS + 4 * m]
                   + h4.w * w2r[3 * NCLS + 4 * m];
        }
      }
    }
    __syncthreads();
  }

  const int n = n0 + zn;
  if (n < NN) {
#pragma unroll
    for (int m = 0; m < 7; ++m) {
      int q = ql + 4 * m;
      if (q < NCLS) z[n * NCLS + q] = zacc[m];
    }
  }
}

extern "C" void kernel_launch(void* const* d_in, const int* in_sizes, int n_in,
                              void* d_out, int out_size, void* d_ws, size_t ws_size,
                              hipStream_t stream) {
  const float* feature = (const float*)d_in[0];
  const float* conv_w  = (const float*)d_in[1];
  const float* conv_b  = (const float*)d_in[2];
  const float* W1      = (const float*)d_in[3];
  const float* b1      = (const float*)d_in[4];
  const float* W2      = (const float*)d_in[5];
  const float* b2      = (const float*)d_in[6];
  const float* adj     = (const float*)d_in[7];
  const int*   erow    = (const int*)d_in[8];
  const int*   ecol    = (const int*)d_in[9];
  float* out = (float*)d_out;

  float* ws = (float*)d_ws;
  size_t o = 0;
  float* x      = ws + o;        o += (size_t)NN * DIN;
  float* ax     = ws + o;        o += (size_t)NN * DIN;
  float* z      = ws + o;        o += (size_t)NN * NCLS;
  int*   counts = (int*)(ws+o);  o += NN;
  int*   offs   = (int*)(ws+o);  o += NN;
  int*   cursor = (int*)(ws+o);  o += NN;
  int*   partial= (int*)(ws+o);  o += 512;
  int*   base   = (int*)(ws+o);  o += 512;
  o = (o + 1) & ~(size_t)1;      // 8B-align for int2
  int2*  csr    = (int2*)(ws+o); o += (size_t)2 * EE;

  // 1) x = relu(conv_sum(feature))
  conv_relu_k<<<8192, 256, 0, stream>>>(feature, conv_w, conv_b, x);
  // 2) CSR build: counts -> scan -> offsets/cursor -> scatter
  zero_int_k<<<512, 256, 0, stream>>>(counts, NN);
  hist_k<<<8192, 256, 0, stream>>>(erow, counts);
  partial_k<<<NB_PART, 256, 0, stream>>>(counts, partial);
  scanpart_k<<<1, 512, 0, stream>>>(partial, base);
  offsets_k<<<NB_PART, 256, 0, stream>>>(counts, base, offs, cursor);
  scatter_k<<<8192, 256, 0, stream>>>(adj, erow, ecol, cursor, csr);
  // 3) ax = A @ x  (gather, no atomics)
  spmm83_g<<<(NN + 3) / 4, 256, 0, stream>>>(offs, counts, csr, x, ax);
  // 4) z = relu(ax @ W1 + b1) @ W2
  fused_mlp_k<<<(NN + 63) / 64, 256, 0, stream>>>(ax, W1, b1, W2, z);
  // 5) out = A @ z + b2  (gather, no atomics)
  spmm25_g<<<(NN / 2 + 3) / 4, 256, 0, stream>>>(offs, counts, csr, z, b2, out);
}

// Round 3
// 1173.976 us; speedup vs baseline: 2.1568x; 1.4584x over previous
//
#include <hip/hip_runtime.h>

#define NN   100000
#define EE   3200000
#define DIN  83
#define DHID 1024
#define NCLS 25

#define NB_PART 391   // ceil(NN/256)

typedef __attribute__((__ext_vector_type__(8))) short sh8;
typedef __attribute__((__ext_vector_type__(4))) float f4_t;

static __device__ __forceinline__ float relu_(float v) { return v > 0.f ? v : 0.f; }

// f32 -> bf16 (RNE)
static __device__ __forceinline__ unsigned short f2bf(float f) {
  unsigned int u = __float_as_uint(f);
  unsigned int r = u + 0x7FFFu + ((u >> 16) & 1u);
  return (unsigned short)(r >> 16);
}

// K1: Conv1d(1->4,k5,p2) + channel-sum + bias + relu, collapsed to a 5-tap conv
__global__ void conv_relu_k(const float* __restrict__ feature,
                            const float* __restrict__ conv_w,
                            const float* __restrict__ conv_b,
                            float* __restrict__ x) {
  float ws0 = conv_w[0] + conv_w[5] + conv_w[10] + conv_w[15];
  float ws1 = conv_w[1] + conv_w[6] + conv_w[11] + conv_w[16];
  float ws2 = conv_w[2] + conv_w[7] + conv_w[12] + conv_w[17];
  float ws3 = conv_w[3] + conv_w[8] + conv_w[13] + conv_w[18];
  float ws4 = conv_w[4] + conv_w[9] + conv_w[14] + conv_w[19];
  float bs  = conv_b[0] + conv_b[1] + conv_b[2] + conv_b[3];
  const int total = NN * DIN;
  for (int idx = blockIdx.x * blockDim.x + threadIdx.x; idx < total;
       idx += gridDim.x * blockDim.x) {
    int n = idx / DIN;
    int i = idx - n * DIN;
    const float* f = feature + n * DIN;
    float acc = bs;
    if (i >= 2)      acc += ws0 * f[i - 2];
    if (i >= 1)      acc += ws1 * f[i - 1];
    acc += ws2 * f[i];
    if (i + 1 < DIN) acc += ws3 * f[i + 1];
    if (i + 2 < DIN) acc += ws4 * f[i + 2];
    x[idx] = relu_(acc);
  }
}

__global__ void zero_int_k(int* __restrict__ p, int total) {
  for (int i = blockIdx.x * blockDim.x + threadIdx.x; i < total;
       i += gridDim.x * blockDim.x)
    p[i] = 0;
}

// W1[83,1024] f32 -> w1t[1024][96] bf16 (transposed, K zero-padded)
__global__ void w1t_k(const float* __restrict__ W1, unsigned short* __restrict__ w1t) {
  int idx = blockIdx.x * blockDim.x + threadIdx.x;
  if (idx >= DHID * 96) return;
  int k = idx / DHID;
  int n = idx - k * DHID;
  float v = (k < DIN) ? W1[k * DHID + n] : 0.f;
  w1t[n * 96 + k] = f2bf(v);
}

// W2[1024,25] f32 -> w2t[32][1024] bf16 (transposed, N zero-padded)
__global__ void w2t_k(const float* __restrict__ W2, unsigned short* __restrict__ w2t) {
  int idx = blockIdx.x * blockDim.x + threadIdx.x;
  if (idx >= 32 * DHID) return;
  int k = idx / 32;
  int n = idx - k * 32;
  float v = (n < NCLS) ? W2[k * NCLS + n] : 0.f;
  w2t[n * DHID + k] = f2bf(v);
}

// ---- CSR build ----
__global__ void hist_k(const int* __restrict__ row, int* __restrict__ counts) {
  for (int e = blockIdx.x * blockDim.x + threadIdx.x; e < EE;
       e += gridDim.x * blockDim.x)
    atomicAdd(&counts[row[e]], 1);
}

__global__ void partial_k(const int* __restrict__ counts, int* __restrict__ partial) {
  __shared__ int sd[256];
  int t = threadIdx.x;
  int i = blockIdx.x * 256 + t;
  sd[t] = (i < NN) ? counts[i] : 0;
  __syncthreads();
  for (int off = 128; off > 0; off >>= 1) {
    if (t < off) sd[t] += sd[t + off];
    __syncthreads();
  }
  if (t == 0) partial[blockIdx.x] = sd[0];
}

__global__ void scanpart_k(const int* __restrict__ partial, int* __restrict__ base) {
  __shared__ int sd[512];
  int t = threadIdx.x;
  int v = (t < NB_PART) ? partial[t] : 0;
  sd[t] = v;
  __syncthreads();
  for (int off = 1; off < 512; off <<= 1) {
    int add = (t >= off) ? sd[t - off] : 0;
    __syncthreads();
    sd[t] += add;
    __syncthreads();
  }
  if (t < NB_PART) base[t] = sd[t] - v;  // exclusive
}

__global__ void offsets_k(const int* __restrict__ counts, const int* __restrict__ base,
                          int* __restrict__ offs, int* __restrict__ cursor) {
  __shared__ int sd[256];
  int t = threadIdx.x;
  int i = blockIdx.x * 256 + t;
  int v = (i < NN) ? counts[i] : 0;
  sd[t] = v;
  __syncthreads();
  for (int off = 1; off < 256; off <<= 1) {
    int add = (t >= off) ? sd[t - off] : 0;
    __syncthreads();
    sd[t] += add;
    __syncthreads();
  }
  if (i < NN) {
    int excl = sd[t] - v + base[blockIdx.x];
    offs[i] = excl;
    cursor[i] = excl;
  }
}

__global__ void scatter_k(const float* __restrict__ vals, const int* __restrict__ row,
                          const int* __restrict__ col, int* __restrict__ cursor,
                          int2* __restrict__ csr) {
  for (int e = blockIdx.x * blockDim.x + threadIdx.x; e < EE;
       e += gridDim.x * blockDim.x) {
    int r = row[e];
    int pos = atomicAdd(&cursor[r], 1);
    csr[pos] = make_int2(col[e], __float_as_int(vals[e]));
  }
}

// ---- gather SpMM, D=83: one wave per row ----
__global__ __launch_bounds__(256) void spmm83_g(
    const int* __restrict__ offs, const int* __restrict__ cnt,
    const int2* __restrict__ csr, const float* __restrict__ x,
    float* __restrict__ ax) {
  int wave = (int)((blockIdx.x * blockDim.x + threadIdx.x) >> 6);
  int lane = threadIdx.x & 63;
  if (wave >= NN) return;
  int s = offs[wave];
  int n = cnt[wave];
  bool hi = lane < (DIN - 64);
  float a0 = 0.f, a1 = 0.f;
  for (int i = 0; i < n; ++i) {
    int2 p = csr[s + i];
    float v = __int_as_float(p.y);
    const float* xr = x + (size_t)p.x * DIN;
    a0 += v * xr[lane];
    if (hi) a1 += v * xr[64 + lane];
  }
  float* dr = ax + (size_t)wave * DIN;
  dr[lane] = a0;
  if (hi) dr[64 + lane] = a1;
}

// ---- gather SpMM, D=25: two rows per wave, +b2 fused ----
__global__ __launch_bounds__(256) void spmm25_g(
    const int* __restrict__ offs, const int* __restrict__ cnt,
    const int2* __restrict__ csr, const float* __restrict__ z,
    const float* __restrict__ b2, float* __restrict__ out) {
  int gw = (int)((blockIdx.x * blockDim.x + threadIdx.x) >> 6);
  int lane = threadIdx.x & 63;
  int half = lane >> 5;
  int d = lane & 31;
  int r = gw * 2 + half;
  if (r >= NN || d >= NCLS) return;
  int s = offs[r];
  int n = cnt[r];
  float acc = 0.f;
  for (int i = 0; i < n; ++i) {
    int2 p = csr[s + i];
    acc += __int_as_float(p.y) * z[(size_t)p.x * NCLS + d];
  }
  out[(size_t)r * NCLS + d] = acc + b2[d];
}

// ---- Fused MLP via bf16 MFMA: z = relu(ax@W1+b1)@W2 ----
// Block = 64 nodes, 4 waves; wave owns one 16-row m-tile; hidden chunked x256.
// No __syncthreads in the main loop: each wave writes/reads only its own hs rows.
__global__ __launch_bounds__(256) void fused_mlp_mfma(
    const float* __restrict__ ax, const unsigned short* __restrict__ w1t,
    const float* __restrict__ b1, const unsigned short* __restrict__ w2t,
    float* __restrict__ z) {
  __shared__ __align__(16) unsigned short axs[64 * 104];  // [64][96] pad->104 (2-way banks)
  __shared__ __align__(16) unsigned short hs[64 * 264];   // [64][256] pad->264
  __shared__ float b1s[DHID];
  const int tid = threadIdx.x;
  const int n0 = blockIdx.x * 64;

  for (int idx = tid; idx < 64 * 96; idx += 256) {
    int m = idx / 96;
    int k = idx - m * 96;
    int node = n0 + m;
    float v = (node < NN && k < DIN) ? ax[(size_t)node * DIN + k] : 0.f;
    axs[m * 104 + k] = f2bf(v);
  }
  for (int i = tid; i < DHID; i += 256) b1s[i] = b1[i];
  __syncthreads();

  const int lane = tid & 63;
  const int w = tid >> 6;
  const int quad = lane >> 4;   // A/B frag: k = quad*8 + j
  const int tn = lane & 15;     // A frag: m; B frag: n; C frag: col
  const int m0 = w * 16;

  sh8 a1[3];
#pragma unroll
  for (int kc = 0; kc < 3; ++kc)
    a1[kc] = *(const sh8*)&axs[(m0 + tn) * 104 + kc * 32 + quad * 8];

  f4_t z0 = {0.f, 0.f, 0.f, 0.f}, z1 = {0.f, 0.f, 0.f, 0.f};

  for (int c = 0; c < 4; ++c) {
    const int cb = c * 256;
    // GEMM1: h_chunk[16,256] = axs_tile[16,96] @ W1[:, cb..cb+255]
#pragma unroll 4
    for (int nt = 0; nt < 16; ++nt) {
      const int ng = cb + nt * 16 + tn;  // this lane's B-frag column
      f4_t acc = {0.f, 0.f, 0.f, 0.f};
#pragma unroll
      for (int kc = 0; kc < 3; ++kc) {
        sh8 b = *(const sh8*)&w1t[(size_t)ng * 96 + kc * 32 + quad * 8];
        acc = __builtin_amdgcn_mfma_f32_16x16x32_bf16(a1[kc], b, acc, 0, 0, 0);
      }
      float bias = b1s[ng];
#pragma unroll
      for (int r = 0; r < 4; ++r) {
        float v = relu_(acc[r] + bias);            // C: col=tn, row=quad*4+r
        hs[(m0 + quad * 4 + r) * 264 + nt * 16 + tn] = f2bf(v);
      }
    }
    // GEMM2: z[16,32] += h_chunk[16,256] @ W2[cb..cb+255, :]
#pragma unroll
    for (int kc = 0; kc < 8; ++kc) {
      sh8 a2 = *(const sh8*)&hs[(m0 + tn) * 264 + kc * 32 + quad * 8];
      sh8 bl = *(const sh8*)&w2t[(size_t)tn * DHID + cb + kc * 32 + quad * 8];
      z0 = __builtin_amdgcn_mfma_f32_16x16x32_bf16(a2, bl, z0, 0, 0, 0);
      sh8 bh = *(const sh8*)&w2t[(size_t)(16 + tn) * DHID + cb + kc * 32 + quad * 8];
      z1 = __builtin_amdgcn_mfma_f32_16x16x32_bf16(a2, bh, z1, 0, 0, 0);
    }
  }

#pragma unroll
  for (int r = 0; r < 4; ++r) {
    int node = n0 + m0 + quad * 4 + r;
    if (node < NN) {
      if (tn < NCLS) z[(size_t)node * NCLS + tn] = z0[r];
      if (16 + tn < NCLS) z[(size_t)node * NCLS + 16 + tn] = z1[r];
    }
  }
}

extern "C" void kernel_launch(void* const* d_in, const int* in_sizes, int n_in,
                              void* d_out, int out_size, void* d_ws, size_t ws_size,
                              hipStream_t stream) {
  const float* feature = (const float*)d_in[0];
  const float* conv_w  = (const float*)d_in[1];
  const float* conv_b  = (const float*)d_in[2];
  const float* W1      = (const float*)d_in[3];
  const float* b1      = (const float*)d_in[4];
  const float* W2      = (const float*)d_in[5];
  const float* b2      = (const float*)d_in[6];
  const float* adj     = (const float*)d_in[7];
  const int*   erow    = (const int*)d_in[8];
  const int*   ecol    = (const int*)d_in[9];
  float* out = (float*)d_out;

  float* ws = (float*)d_ws;
  size_t o = 0;
  float* x      = ws + o;        o += (size_t)NN * DIN;
  float* ax     = ws + o;        o += (size_t)NN * DIN;
  float* z      = ws + o;        o += (size_t)NN * NCLS;
  int*   counts = (int*)(ws+o);  o += NN;
  int*   offs   = (int*)(ws+o);  o += NN;
  int*   cursor = (int*)(ws+o);  o += NN;
  int*   partial= (int*)(ws+o);  o += 512;
  int*   base   = (int*)(ws+o);  o += 512;
  o = (o + 3) & ~(size_t)3;      // 16B align
  unsigned short* w1t = (unsigned short*)(ws+o); o += (size_t)DHID * 96 / 2;
  unsigned short* w2t = (unsigned short*)(ws+o); o += (size_t)32 * DHID / 2;
  o = (o + 1) & ~(size_t)1;      // 8B align for int2
  int2*  csr    = (int2*)(ws+o); o += (size_t)2 * EE;

  // 1) x = relu(conv_sum(feature)); weight prep
  conv_relu_k<<<8192, 256, 0, stream>>>(feature, conv_w, conv_b, x);
  w1t_k<<<(DHID * 96 + 255) / 256, 256, 0, stream>>>(W1, w1t);
  w2t_k<<<(32 * DHID + 255) / 256, 256, 0, stream>>>(W2, w2t);
  // 2) CSR build
  zero_int_k<<<512, 256, 0, stream>>>(counts, NN);
  hist_k<<<8192, 256, 0, stream>>>(erow, counts);
  partial_k<<<NB_PART, 256, 0, stream>>>(counts, partial);
  scanpart_k<<<1, 512, 0, stream>>>(partial, base);
  offsets_k<<<NB_PART, 256, 0, stream>>>(counts, base, offs, cursor);
  scatter_k<<<8192, 256, 0, stream>>>(adj, erow, ecol, cursor, csr);
  // 3) ax = A @ x (gather)
  spmm83_g<<<(NN + 3) / 4, 256, 0, stream>>>(offs, counts, csr, x, ax);
  // 4) z = relu(ax @ W1 + b1) @ W2 via bf16 MFMA
  fused_mlp_mfma<<<(NN + 63) / 64, 256, 0, stream>>>(ax, w1t, b1, w2t, z);
  // 5) out = A @ z + b2 (gather)
  spmm25_g<<<(NN / 2 + 3) / 4, 256, 0, stream>>>(offs, counts, csr, z, b2, out);
}

// Round 4
// 736.167 us; speedup vs baseline: 3.4395x; 1.5947x over previous
//
#include <hip/hip_runtime.h>

#define NN   100000
#define EE   3200000
#define DIN  83
#define DHID 1024
#define NCLS 25
#define XPAD 96    // x/ax bf16 row padding (192 B = 3 cache lines)
#define ZPAD 32    // z bf16 row padding (64 B = 1 cache line)

#define NB_PART 391   // ceil(NN/256)

typedef __attribute__((__ext_vector_type__(8))) short sh8;
typedef __attribute__((__ext_vector_type__(4))) float f4_t;

static __device__ __forceinline__ float relu_(float v) { return v > 0.f ? v : 0.f; }

// f32 -> bf16 (RNE)
static __device__ __forceinline__ unsigned short f2bf(float f) {
  unsigned int u = __float_as_uint(f);
  unsigned int r = u + 0x7FFFu + ((u >> 16) & 1u);
  return (unsigned short)(r >> 16);
}
// packed bf16 pair -> two f32
static __device__ __forceinline__ float bflo(unsigned int q) {
  return __uint_as_float(q << 16);
}
static __device__ __forceinline__ float bfhi(unsigned int q) {
  return __uint_as_float(q & 0xFFFF0000u);
}

// K1: Conv1d(1->4,k5,p2) + channel-sum + bias + relu -> bf16 x[NN][96]
__global__ void conv_relu_k(const float* __restrict__ feature,
                            const float* __restrict__ conv_w,
                            const float* __restrict__ conv_b,
                            unsigned short* __restrict__ x) {
  float ws0 = conv_w[0] + conv_w[5] + conv_w[10] + conv_w[15];
  float ws1 = conv_w[1] + conv_w[6] + conv_w[11] + conv_w[16];
  float ws2 = conv_w[2] + conv_w[7] + conv_w[12] + conv_w[17];
  float ws3 = conv_w[3] + conv_w[8] + conv_w[13] + conv_w[18];
  float ws4 = conv_w[4] + conv_w[9] + conv_w[14] + conv_w[19];
  float bs  = conv_b[0] + conv_b[1] + conv_b[2] + conv_b[3];
  const int total = NN * XPAD;
  for (int idx = blockIdx.x * blockDim.x + threadIdx.x; idx < total;
       idx += gridDim.x * blockDim.x) {
    int n = idx / XPAD;
    int i = idx - n * XPAD;
    unsigned short o = 0;
    if (i < DIN) {
      const float* f = feature + (size_t)n * DIN;
      float acc = bs;
      if (i >= 2)      acc += ws0 * f[i - 2];
      if (i >= 1)      acc += ws1 * f[i - 1];
      acc += ws2 * f[i];
      if (i + 1 < DIN) acc += ws3 * f[i + 1];
      if (i + 2 < DIN) acc += ws4 * f[i + 2];
      o = f2bf(relu_(acc));
    }
    x[idx] = o;
  }
}

__global__ void zero_int_k(int* __restrict__ p, int total) {
  for (int i = blockIdx.x * blockDim.x + threadIdx.x; i < total;
       i += gridDim.x * blockDim.x)
    p[i] = 0;
}

// W1[83,1024] f32 -> w1t[1024][96] bf16 (transposed, K zero-padded)
__global__ void w1t_k(const float* __restrict__ W1, unsigned short* __restrict__ w1t) {
  int idx = blockIdx.x * blockDim.x + threadIdx.x;
  if (idx >= DHID * XPAD) return;
  int k = idx / DHID;
  int n = idx - k * DHID;
  float v = (k < DIN) ? W1[k * DHID + n] : 0.f;
  w1t[n * XPAD + k] = f2bf(v);
}

// W2[1024,25] f32 -> w2t[32][1024] bf16 (transposed, N zero-padded)
__global__ void w2t_k(const float* __restrict__ W2, unsigned short* __restrict__ w2t) {
  int idx = blockIdx.x * blockDim.x + threadIdx.x;
  if (idx >= 32 * DHID) return;
  int k = idx / 32;
  int n = idx - k * 32;
  float v = (n < NCLS) ? W2[k * NCLS + n] : 0.f;
  w2t[n * DHID + k] = f2bf(v);
}

// ---- CSR build ----
__global__ void hist_k(const int* __restrict__ row, int* __restrict__ counts) {
  for (int e = blockIdx.x * blockDim.x + threadIdx.x; e < EE;
       e += gridDim.x * blockDim.x)
    atomicAdd(&counts[row[e]], 1);
}

__global__ void partial_k(const int* __restrict__ counts, int* __restrict__ partial) {
  __shared__ int sd[256];
  int t = threadIdx.x;
  int i = blockIdx.x * 256 + t;
  sd[t] = (i < NN) ? counts[i] : 0;
  __syncthreads();
  for (int off = 128; off > 0; off >>= 1) {
    if (t < off) sd[t] += sd[t + off];
    __syncthreads();
  }
  if (t == 0) partial[blockIdx.x] = sd[0];
}

__global__ void scanpart_k(const int* __restrict__ partial, int* __restrict__ base) {
  __shared__ int sd[512];
  int t = threadIdx.x;
  int v = (t < NB_PART) ? partial[t] : 0;
  sd[t] = v;
  __syncthreads();
  for (int off = 1; off < 512; off <<= 1) {
    int add = (t >= off) ? sd[t - off] : 0;
    __syncthreads();
    sd[t] += add;
    __syncthreads();
  }
  if (t < NB_PART) base[t] = sd[t] - v;  // exclusive
}

__global__ void offsets_k(const int* __restrict__ counts, const int* __restrict__ base,
                          int* __restrict__ offs, int* __restrict__ cursor) {
  __shared__ int sd[256];
  int t = threadIdx.x;
  int i = blockIdx.x * 256 + t;
  int v = (i < NN) ? counts[i] : 0;
  sd[t] = v;
  __syncthreads();
  for (int off = 1; off < 256; off <<= 1) {
    int add = (t >= off) ? sd[t - off] : 0;
    __syncthreads();
    sd[t] += add;
    __syncthreads();
  }
  if (i < NN) {
    int excl = sd[t] - v + base[blockIdx.x];
    offs[i] = excl;
    cursor[i] = excl;
  }
}

__global__ void scatter_k(const float* __restrict__ vals, const int* __restrict__ row,
                          const int* __restrict__ col, int* __restrict__ cursor,
                          int2* __restrict__ csr) {
  for (int e = blockIdx.x * blockDim.x + threadIdx.x; e < EE;
       e += gridDim.x * blockDim.x) {
    int r = row[e];
    int pos = atomicAdd(&cursor[r], 1);
    csr[pos] = make_int2(col[e], __float_as_int(vals[e]));
  }
}

// ---- gather SpMM, D=83(96 bf16): one wave per row, ILP-4 edge unroll ----
__global__ __launch_bounds__(256) void spmm83_g(
    const int* __restrict__ offs, const int* __restrict__ cnt,
    const int2* __restrict__ csr, const unsigned short* __restrict__ x,
    unsigned short* __restrict__ ax) {
  int wave = (int)((blockIdx.x * blockDim.x + threadIdx.x) >> 6);
  int lane = threadIdx.x & 63;
  if (wave >= NN) return;
  int s = offs[wave];
  int n = cnt[wave];
  const bool act = lane < 48;         // 48 lanes x short2 = 96 dims
  const int d2 = lane * 2;
  float a0 = 0.f, a1 = 0.f;
  int i = 0;
  for (; i + 4 <= n; i += 4) {
    int2 p0 = csr[s + i + 0];
    int2 p1 = csr[s + i + 1];
    int2 p2 = csr[s + i + 2];
    int2 p3 = csr[s + i + 3];
    if (act) {
      unsigned int q0 = *(const unsigned int*)&x[(size_t)p0.x * XPAD + d2];
      unsigned int q1 = *(const unsigned int*)&x[(size_t)p1.x * XPAD + d2];
      unsigned int q2 = *(const unsigned int*)&x[(size_t)p2.x * XPAD + d2];
      unsigned int q3 = *(const unsigned int*)&x[(size_t)p3.x * XPAD + d2];
      float v0 = __int_as_float(p0.y), v1 = __int_as_float(p1.y);
      float v2 = __int_as_float(p2.y), v3 = __int_as_float(p3.y);
      a0 += v0 * bflo(q0) + v1 * bflo(q1) + v2 * bflo(q2) + v3 * bflo(q3);
      a1 += v0 * bfhi(q0) + v1 * bfhi(q1) + v2 * bfhi(q2) + v3 * bfhi(q3);
    }
  }
  for (; i < n; ++i) {
    int2 p = csr[s + i];
    if (act) {
      unsigned int q = *(const unsigned int*)&x[(size_t)p.x * XPAD + d2];
      float v = __int_as_float(p.y);
      a0 += v * bflo(q);
      a1 += v * bfhi(q);
    }
  }
  if (act) {
    unsigned int o = (unsigned int)f2bf(a0) | ((unsigned int)f2bf(a1) << 16);
    *(unsigned int*)&ax[(size_t)wave * XPAD + d2] = o;
  }
}

// ---- gather SpMM, D=25(32 bf16): 4 rows per wave (16 lanes each), +b2 fused ----
__global__ __launch_bounds__(256) void spmm25_g(
    const int* __restrict__ offs, const int* __restrict__ cnt,
    const int2* __restrict__ csr, const unsigned short* __restrict__ zb,
    const float* __restrict__ b2, float* __restrict__ out) {
  int gw = (int)((blockIdx.x * blockDim.x + threadIdx.x) >> 6);
  int lane = threadIdx.x & 63;
  int sub = lane >> 4;
  int d2 = (lane & 15) * 2;
  int r = gw * 4 + sub;
  if (r >= NN) return;
  int s = offs[r];
  int n = cnt[r];
  float a0 = 0.f, a1 = 0.f;
  int i = 0;
  for (; i + 2 <= n; i += 2) {
    int2 p0 = csr[s + i];
    int2 p1 = csr[s + i + 1];
    unsigned int q0 = *(const unsigned int*)&zb[(size_t)p0.x * ZPAD + d2];
    unsigned int q1 = *(const unsigned int*)&zb[(size_t)p1.x * ZPAD + d2];
    float v0 = __int_as_float(p0.y), v1 = __int_as_float(p1.y);
    a0 += v0 * bflo(q0) + v1 * bflo(q1);
    a1 += v0 * bfhi(q0) + v1 * bfhi(q1);
  }
  for (; i < n; ++i) {
    int2 p = csr[s + i];
    unsigned int q = *(const unsigned int*)&zb[(size_t)p.x * ZPAD + d2];
    float v = __int_as_float(p.y);
    a0 += v * bflo(q);
    a1 += v * bfhi(q);
  }
  if (d2 < NCLS)     out[(size_t)r * NCLS + d2]     = a0 + b2[d2];
  if (d2 + 1 < NCLS) out[(size_t)r * NCLS + d2 + 1] = a1 + b2[d2 + 1];
}

// ---- Fused MLP via bf16 MFMA: z = relu(ax@W1+b1)@W2, z -> bf16[NN][32] ----
__global__ __launch_bounds__(256) void fused_mlp_mfma(
    const unsigned short* __restrict__ axg, const unsigned short* __restrict__ w1t,
    const float* __restrict__ b1, const unsigned short* __restrict__ w2t,
    unsigned short* __restrict__ zb) {
  __shared__ __align__(16) unsigned short axs[64 * 104];  // [64][96] pad->104
  __shared__ __align__(16) unsigned short hs[64 * 264];   // [64][256] pad->264
  __shared__ float b1s[DHID];
  const int tid = threadIdx.x;
  const int n0 = blockIdx.x * 64;

  for (int idx = tid; idx < 64 * 12; idx += 256) {   // 12 sh8 chunks per row
    int m = idx / 12;
    int c8 = idx - m * 12;
    int node = n0 + m;
    sh8 v = {0, 0, 0, 0, 0, 0, 0, 0};
    if (node < NN) v = *(const sh8*)&axg[(size_t)node * XPAD + c8 * 8];
    *(sh8*)&axs[m * 104 + c8 * 8] = v;
  }
  for (int i = tid; i < DHID; i += 256) b1s[i] = b1[i];
  __syncthreads();

  const int lane = tid & 63;
  const int w = tid >> 6;
  const int quad = lane >> 4;   // A/B frag: k = quad*8 + j
  const int tn = lane & 15;     // A frag: m; B frag: n; C frag: col
  const int m0 = w * 16;

  sh8 a1[3];
#pragma unroll
  for (int kc = 0; kc < 3; ++kc)
    a1[kc] = *(const sh8*)&axs[(m0 + tn) * 104 + kc * 32 + quad * 8];

  f4_t z0 = {0.f, 0.f, 0.f, 0.f}, z1 = {0.f, 0.f, 0.f, 0.f};

  for (int c = 0; c < 4; ++c) {
    const int cb = c * 256;
    // GEMM1: h_chunk[16,256] = axs_tile[16,96] @ W1[:, cb..cb+255]
#pragma unroll 4
    for (int nt = 0; nt < 16; ++nt) {
      const int ng = cb + nt * 16 + tn;
      f4_t acc = {0.f, 0.f, 0.f, 0.f};
#pragma unroll
      for (int kc = 0; kc < 3; ++kc) {
        sh8 b = *(const sh8*)&w1t[(size_t)ng * XPAD + kc * 32 + quad * 8];
        acc = __builtin_amdgcn_mfma_f32_16x16x32_bf16(a1[kc], b, acc, 0, 0, 0);
      }
      float bias = b1s[ng];
#pragma unroll
      for (int r = 0; r < 4; ++r) {
        float v = relu_(acc[r] + bias);            // C: col=tn, row=quad*4+r
        hs[(m0 + quad * 4 + r) * 264 + nt * 16 + tn] = f2bf(v);
      }
    }
    // GEMM2: z[16,32] += h_chunk[16,256] @ W2[cb..cb+255, :]
#pragma unroll
    for (int kc = 0; kc < 8; ++kc) {
      sh8 a2 = *(const sh8*)&hs[(m0 + tn) * 264 + kc * 32 + quad * 8];
      sh8 bl = *(const sh8*)&w2t[(size_t)tn * DHID + cb + kc * 32 + quad * 8];
      z0 = __builtin_amdgcn_mfma_f32_16x16x32_bf16(a2, bl, z0, 0, 0, 0);
      sh8 bh = *(const sh8*)&w2t[(size_t)(16 + tn) * DHID + cb + kc * 32 + quad * 8];
      z1 = __builtin_amdgcn_mfma_f32_16x16x32_bf16(a2, bh, z1, 0, 0, 0);
    }
  }

#pragma unroll
  for (int r = 0; r < 4; ++r) {
    int node = n0 + m0 + quad * 4 + r;
    if (node < NN) {
      zb[(size_t)node * ZPAD + tn]      = f2bf(z0[r]);
      zb[(size_t)node * ZPAD + 16 + tn] = f2bf(z1[r]);
    }
  }
}

extern "C" void kernel_launch(void* const* d_in, const int* in_sizes, int n_in,
                              void* d_out, int out_size, void* d_ws, size_t ws_size,
                              hipStream_t stream) {
  const float* feature = (const float*)d_in[0];
  const float* conv_w  = (const float*)d_in[1];
  const float* conv_b  = (const float*)d_in[2];
  const float* W1      = (const float*)d_in[3];
  const float* b1      = (const float*)d_in[4];
  const float* W2      = (const float*)d_in[5];
  const float* b2      = (const float*)d_in[6];
  const float* adj     = (const float*)d_in[7];
  const int*   erow    = (const int*)d_in[8];
  const int*   ecol    = (const int*)d_in[9];
  float* out = (float*)d_out;

  char* B = (char*)d_ws;
  size_t o = 0;
  auto alloc = [&](size_t bytes, size_t align) -> void* {
    o = (o + align - 1) & ~(align - 1);
    void* p = B + o;
    o += bytes;
    return p;
  };
  unsigned short* x    = (unsigned short*)alloc((size_t)NN * XPAD * 2, 16);
  unsigned short* ax   = (unsigned short*)alloc((size_t)NN * XPAD * 2, 16);
  unsigned short* zb   = (unsigned short*)alloc((size_t)NN * ZPAD * 2, 16);
  int*   counts  = (int*)alloc((size_t)NN * 4, 16);
  int*   offs    = (int*)alloc((size_t)NN * 4, 16);
  int*   cursor  = (int*)alloc((size_t)NN * 4, 16);
  int*   partial = (int*)alloc(512 * 4, 16);
  int*   base    = (int*)alloc(512 * 4, 16);
  unsigned short* w1t = (unsigned short*)alloc((size_t)DHID * XPAD * 2, 16);
  unsigned short* w2t = (unsigned short*)alloc((size_t)32 * DHID * 2, 16);
  int2*  csr     = (int2*)alloc((size_t)EE * 8, 16);

  // 1) x = relu(conv_sum(feature)) -> bf16 [NN][96]; weight prep
  conv_relu_k<<<8192, 256, 0, stream>>>(feature, conv_w, conv_b, x);
  w1t_k<<<(DHID * XPAD + 255) / 256, 256, 0, stream>>>(W1, w1t);
  w2t_k<<<(32 * DHID + 255) / 256, 256, 0, stream>>>(W2, w2t);
  // 2) CSR build
  zero_int_k<<<512, 256, 0, stream>>>(counts, NN);
  hist_k<<<8192, 256, 0, stream>>>(erow, counts);
  partial_k<<<NB_PART, 256, 0, stream>>>(counts, partial);
  scanpart_k<<<1, 512, 0, stream>>>(partial, base);
  offsets_k<<<NB_PART, 256, 0, stream>>>(counts, base, offs, cursor);
  scatter_k<<<8192, 256, 0, stream>>>(adj, erow, ecol, cursor, csr);
  // 3) ax = A @ x (gather, bf16 rows, ILP-4)
  spmm83_g<<<(NN + 3) / 4, 256, 0, stream>>>(offs, counts, csr, x, ax);
  // 4) z = relu(ax @ W1 + b1) @ W2 via bf16 MFMA -> bf16 [NN][32]
  fused_mlp_mfma<<<(NN + 63) / 64, 256, 0, stream>>>(ax, w1t, b1, w2t, zb);
  // 5) out = A @ z + b2 (gather, 1 line per edge)
  spmm25_g<<<(NN + 15) / 16, 256, 0, stream>>>(offs, counts, csr, zb, b2, out);
}

// Round 5
// 669.254 us; speedup vs baseline: 3.7834x; 1.1000x over previous
//
#include <hip/hip_runtime.h>

#define NN   100000
#define EE   3200000
#define DIN  83
#define DHID 1024
#define NCLS 25
#define XPAD 96    // x/ax bf16 row padding (192 B = 3 cache lines)
#define ZPAD 32    // z bf16 row padding (64 B = 1 cache line)

#define NB_PART 391   // ceil(NN/256)
#define NBK     391   // buckets of 256 rows (row >> 8)
#define CHUNK   8192  // edges per partition block

typedef __attribute__((__ext_vector_type__(8))) short sh8;
typedef __attribute__((__ext_vector_type__(4))) float f4_t;

static __device__ __forceinline__ float relu_(float v) { return v > 0.f ? v : 0.f; }

// f32 -> bf16 (RNE)
static __device__ __forceinline__ unsigned short f2bf(float f) {
  unsigned int u = __float_as_uint(f);
  unsigned int r = u + 0x7FFFu + ((u >> 16) & 1u);
  return (unsigned short)(r >> 16);
}
// packed bf16 pair -> two f32
static __device__ __forceinline__ float bflo(unsigned int q) {
  return __uint_as_float(q << 16);
}
static __device__ __forceinline__ float bfhi(unsigned int q) {
  return __uint_as_float(q & 0xFFFF0000u);
}

// K1: Conv1d(1->4,k5,p2) + channel-sum + bias + relu -> bf16 x[NN][96]
__global__ void conv_relu_k(const float* __restrict__ feature,
                            const float* __restrict__ conv_w,
                            const float* __restrict__ conv_b,
                            unsigned short* __restrict__ x) {
  float ws0 = conv_w[0] + conv_w[5] + conv_w[10] + conv_w[15];
  float ws1 = conv_w[1] + conv_w[6] + conv_w[11] + conv_w[16];
  float ws2 = conv_w[2] + conv_w[7] + conv_w[12] + conv_w[17];
  float ws3 = conv_w[3] + conv_w[8] + conv_w[13] + conv_w[18];
  float ws4 = conv_w[4] + conv_w[9] + conv_w[14] + conv_w[19];
  float bs  = conv_b[0] + conv_b[1] + conv_b[2] + conv_b[3];
  const int total = NN * XPAD;
  for (int idx = blockIdx.x * blockDim.x + threadIdx.x; idx < total;
       idx += gridDim.x * blockDim.x) {
    int n = idx / XPAD;
    int i = idx - n * XPAD;
    unsigned short o = 0;
    if (i < DIN) {
      const float* f = feature + (size_t)n * DIN;
      float acc = bs;
      if (i >= 2)      acc += ws0 * f[i - 2];
      if (i >= 1)      acc += ws1 * f[i - 1];
      acc += ws2 * f[i];
      if (i + 1 < DIN) acc += ws3 * f[i + 1];
      if (i + 2 < DIN) acc += ws4 * f[i + 2];
      o = f2bf(relu_(acc));
    }
    x[idx] = o;
  }
}

__global__ void zero_int_k(int* __restrict__ p, int total) {
  for (int i = blockIdx.x * blockDim.x + threadIdx.x; i < total;
       i += gridDim.x * blockDim.x)
    p[i] = 0;
}

// W1[83,1024] f32 -> w1t[1024][96] bf16 (transposed, K zero-padded)
__global__ void w1t_k(const float* __restrict__ W1, unsigned short* __restrict__ w1t) {
  int idx = blockIdx.x * blockDim.x + threadIdx.x;
  if (idx >= DHID * XPAD) return;
  int k = idx / DHID;
  int n = idx - k * DHID;
  float v = (k < DIN) ? W1[k * DHID + n] : 0.f;
  w1t[n * XPAD + k] = f2bf(v);
}

// W2[1024,25] f32 -> w2t[32][1024] bf16 (transposed, N zero-padded)
__global__ void w2t_k(const float* __restrict__ W2, unsigned short* __restrict__ w2t) {
  int idx = blockIdx.x * blockDim.x + threadIdx.x;
  if (idx >= 32 * DHID) return;
  int k = idx / 32;
  int n = idx - k * 32;
  float v = (n < NCLS) ? W2[k * NCLS + n] : 0.f;
  w2t[n * DHID + k] = f2bf(v);
}

// ---- CSR build ----
__global__ void hist_k(const int* __restrict__ row, int* __restrict__ counts) {
  for (int e = blockIdx.x * blockDim.x + threadIdx.x; e < EE;
       e += gridDim.x * blockDim.x)
    atomicAdd(&counts[row[e]], 1);
}

__global__ void partial_k(const int* __restrict__ counts, int* __restrict__ partial) {
  __shared__ int sd[256];
  int t = threadIdx.x;
  int i = blockIdx.x * 256 + t;
  sd[t] = (i < NN) ? counts[i] : 0;
  __syncthreads();
  for (int off = 128; off > 0; off >>= 1) {
    if (t < off) sd[t] += sd[t + off];
    __syncthreads();
  }
  if (t == 0) partial[blockIdx.x] = sd[0];
}

__global__ void scanpart_k(const int* __restrict__ partial, int* __restrict__ base) {
  __shared__ int sd[512];
  int t = threadIdx.x;
  int v = (t < NB_PART) ? partial[t] : 0;
  sd[t] = v;
  __syncthreads();
  for (int off = 1; off < 512; off <<= 1) {
    int add = (t >= off) ? sd[t - off] : 0;
    __syncthreads();
    sd[t] += add;
    __syncthreads();
  }
  if (t < NB_PART) base[t] = sd[t] - v;  // exclusive
}

// per-block scan -> offs; also seed bucket cursors gcur (line-padded, stride 16)
__global__ void offsets_k(const int* __restrict__ counts, const int* __restrict__ base,
                          int* __restrict__ offs, int* __restrict__ gcur) {
  __shared__ int sd[256];
  int t = threadIdx.x;
  int i = blockIdx.x * 256 + t;
  int v = (i < NN) ? counts[i] : 0;
  sd[t] = v;
  __syncthreads();
  for (int off = 1; off < 256; off <<= 1) {
    int add = (t >= off) ? sd[t - off] : 0;
    __syncthreads();
    sd[t] += add;
    __syncthreads();
  }
  if (i < NN) {
    int excl = sd[t] - v + base[blockIdx.x];
    offs[i] = excl;
    if ((i & 255) == 0) gcur[(i >> 8) * 16] = excl;  // bucket start cursor
  }
}

// Pass 1: partition edges into 391 buckets (row>>8), bucket-major tmp.
// LDS staging -> coalesced flush; one reservation atomic per bucket per block.
__global__ __launch_bounds__(256) void partition_k(
    const float* __restrict__ vals, const int* __restrict__ row,
    const int* __restrict__ col, int* __restrict__ gcur,
    int2* __restrict__ tmp) {
  __shared__ int cnt[NBK];
  __shared__ int sc[512];     // scan scratch
  __shared__ int es[NBK];     // exclusive start per bucket
  __shared__ int lcur[NBK];
  __shared__ int gbase[NBK];
  __shared__ int2 staged[CHUNK];
  const int tid = threadIdx.x;
  const int cb = blockIdx.x * CHUNK;
  const int csize = (cb + CHUNK <= EE) ? CHUNK : (EE - cb);

  for (int b = tid; b < NBK; b += 256) cnt[b] = 0;
  __syncthreads();
  // count
  for (int i = tid; i < csize; i += 256)
    atomicAdd(&cnt[row[cb + i] >> 8], 1);
  __syncthreads();
  // scan 391 counts (padded 512, 2 slots/thread Hillis-Steele)
  sc[tid]       = (tid < NBK) ? cnt[tid] : 0;
  sc[tid + 256] = (tid + 256 < NBK) ? cnt[tid + 256] : 0;
  __syncthreads();
  for (int off = 1; off < 512; off <<= 1) {
    int a0 = (tid >= off) ? sc[tid - off] : 0;
    int a1 = (tid + 256 >= off) ? sc[tid + 256 - off] : 0;
    __syncthreads();
    sc[tid] += a0;
    sc[tid + 256] += a1;
    __syncthreads();
  }
  for (int b = tid; b < NBK; b += 256) {
    int e = sc[b] - cnt[b];   // exclusive
    es[b] = e;
    lcur[b] = e;
  }
  __syncthreads();
  // reserve global space per bucket
  for (int b = tid; b < NBK; b += 256)
    gbase[b] = cnt[b] ? atomicAdd(&gcur[b * 16], cnt[b]) : 0;
  __syncthreads();
  // stage bucket-major into LDS (row&255 packed into bits 17..24 of col)
  for (int i = tid; i < csize; i += 256) {
    int r = row[cb + i];
    int lpos = atomicAdd(&lcur[r >> 8], 1);
    staged[lpos] = make_int2(col[cb + i] | ((r & 255) << 17),
                             __float_as_int(vals[cb + i]));
  }
  __syncthreads();
  // coalesced flush: consecutive staged slots -> consecutive global slots per bucket
  for (int j = tid; j < csize; j += 256) {
    int lo = 0, hi = NBK - 1;          // largest b with es[b] <= j
    while (lo < hi) {
      int mid = (lo + hi + 1) >> 1;
      if (es[mid] <= j) lo = mid; else hi = mid - 1;
    }
    tmp[gbase[lo] + (j - es[lo])] = staged[j];
  }
}

// Pass 2: per-bucket fine scatter. Block owns 256 rows + a ~128KB csr window;
// row cursors in LDS, writes stay CU/L2-local -> lines coalesce before eviction.
__global__ __launch_bounds__(256) void fine_scatter_k(
    const int* __restrict__ offs, const int2* __restrict__ tmp,
    int2* __restrict__ csr) {
  __shared__ int lcur[256];
  const int tid = threadIdx.x;
  const int b = blockIdx.x;
  const int r0 = b * 256;
  const int nr = (r0 + 256 <= NN) ? 256 : (NN - r0);
  if (tid < nr) lcur[tid] = offs[r0 + tid];   // absolute cursors
  __syncthreads();
  const int gstart = offs[r0];
  const int gend = (b == NBK - 1) ? EE : offs[r0 + 256];
  for (int i = tid; i < gend - gstart; i += 256) {
    int2 p = tmp[gstart + i];
    int rl = p.x >> 17;
    int pos = atomicAdd(&lcur[rl], 1);
    csr[pos] = make_int2(p.x & 0x1FFFF, p.y);
  }
}

// ---- gather SpMM, D=83(96 bf16): one wave per row, ILP-8 edge unroll ----
__global__ __launch_bounds__(256) void spmm83_g(
    const int* __restrict__ offs, const int* __restrict__ cnt,
    const int2* __restrict__ csr, const unsigned short* __restrict__ x,
    unsigned short* __restrict__ ax) {
  int wave = (int)((blockIdx.x * blockDim.x + threadIdx.x) >> 6);
  int lane = threadIdx.x & 63;
  if (wave >= NN) return;
  int s = offs[wave];
  int n = cnt[wave];
  const bool act = lane < 48;         // 48 lanes x short2 = 96 dims
  const int d2 = lane * 2;
  float a0 = 0.f, a1 = 0.f;
  int i = 0;
  for (; i + 8 <= n; i += 8) {
    int2 p[8];
#pragma unroll
    for (int u = 0; u < 8; ++u) p[u] = csr[s + i + u];
    if (act) {
      unsigned int q[8];
#pragma unroll
      for (int u = 0; u < 8; ++u)
        q[u] = *(const unsigned int*)&x[(size_t)p[u].x * XPAD + d2];
#pragma unroll
      for (int u = 0; u < 8; ++u) {
        float v = __int_as_float(p[u].y);
        a0 += v * bflo(q[u]);
        a1 += v * bfhi(q[u]);
      }
    }
  }
  for (; i < n; ++i) {
    int2 p = csr[s + i];
    if (act) {
      unsigned int q = *(const unsigned int*)&x[(size_t)p.x * XPAD + d2];
      float v = __int_as_float(p.y);
      a0 += v * bflo(q);
      a1 += v * bfhi(q);
    }
  }
  if (act) {
    unsigned int o = (unsigned int)f2bf(a0) | ((unsigned int)f2bf(a1) << 16);
    *(unsigned int*)&ax[(size_t)wave * XPAD + d2] = o;
  }
}

// ---- gather SpMM, D=25(32 bf16): 4 rows per wave (16 lanes each), ILP-4, +b2 ----
__global__ __launch_bounds__(256) void spmm25_g(
    const int* __restrict__ offs, const int* __restrict__ cnt,
    const int2* __restrict__ csr, const unsigned short* __restrict__ zb,
    const float* __restrict__ b2, float* __restrict__ out) {
  int gw = (int)((blockIdx.x * blockDim.x + threadIdx.x) >> 6);
  int lane = threadIdx.x & 63;
  int sub = lane >> 4;
  int d2 = (lane & 15) * 2;
  int r = gw * 4 + sub;
  if (r >= NN) return;
  int s = offs[r];
  int n = cnt[r];
  float a0 = 0.f, a1 = 0.f;
  int i = 0;
  for (; i + 4 <= n; i += 4) {
    int2 p0 = csr[s + i + 0];
    int2 p1 = csr[s + i + 1];
    int2 p2 = csr[s + i + 2];
    int2 p3 = csr[s + i + 3];
    unsigned int q0 = *(const unsigned int*)&zb[(size_t)p0.x * ZPAD + d2];
    unsigned int q1 = *(const unsigned int*)&zb[(size_t)p1.x * ZPAD + d2];
    unsigned int q2 = *(const unsigned int*)&zb[(size_t)p2.x * ZPAD + d2];
    unsigned int q3 = *(const unsigned int*)&zb[(size_t)p3.x * ZPAD + d2];
    float v0 = __int_as_float(p0.y), v1 = __int_as_float(p1.y);
    float v2 = __int_as_float(p2.y), v3 = __int_as_float(p3.y);
    a0 += v0 * bflo(q0) + v1 * bflo(q1) + v2 * bflo(q2) + v3 * bflo(q3);
    a1 += v0 * bfhi(q0) + v1 * bfhi(q1) + v2 * bfhi(q2) + v3 * bfhi(q3);
  }
  for (; i < n; ++i) {
    int2 p = csr[s + i];
    unsigned int q = *(const unsigned int*)&zb[(size_t)p.x * ZPAD + d2];
    float v = __int_as_float(p.y);
    a0 += v * bflo(q);
    a1 += v * bfhi(q);
  }
  if (d2 < NCLS)     out[(size_t)r * NCLS + d2]     = a0 + b2[d2];
  if (d2 + 1 < NCLS) out[(size_t)r * NCLS + d2 + 1] = a1 + b2[d2 + 1];
}

// ---- Fused MLP via bf16 MFMA: z = relu(ax@W1+b1)@W2, z -> bf16[NN][32] ----
__global__ __launch_bounds__(256) void fused_mlp_mfma(
    const unsigned short* __restrict__ axg, const unsigned short* __restrict__ w1t,
    const float* __restrict__ b1, const unsigned short* __restrict__ w2t,
    unsigned short* __restrict__ zb) {
  __shared__ __align__(16) unsigned short axs[64 * 104];  // [64][96] pad->104
  __shared__ __align__(16) unsigned short hs[64 * 264];   // [64][256] pad->264
  __shared__ float b1s[DHID];
  const int tid = threadIdx.x;
  const int n0 = blockIdx.x * 64;

  for (int idx = tid; idx < 64 * 12; idx += 256) {   // 12 sh8 chunks per row
    int m = idx / 12;
    int c8 = idx - m * 12;
    int node = n0 + m;
    sh8 v = {0, 0, 0, 0, 0, 0, 0, 0};
    if (node < NN) v = *(const sh8*)&axg[(size_t)node * XPAD + c8 * 8];
    *(sh8*)&axs[m * 104 + c8 * 8] = v;
  }
  for (int i = tid; i < DHID; i += 256) b1s[i] = b1[i];
  __syncthreads();

  const int lane = tid & 63;
  const int w = tid >> 6;
  const int quad = lane >> 4;   // A/B frag: k = quad*8 + j
  const int tn = lane & 15;     // A frag: m; B frag: n; C frag: col
  const int m0 = w * 16;

  sh8 a1[3];
#pragma unroll
  for (int kc = 0; kc < 3; ++kc)
    a1[kc] = *(const sh8*)&axs[(m0 + tn) * 104 + kc * 32 + quad * 8];

  f4_t z0 = {0.f, 0.f, 0.f, 0.f}, z1 = {0.f, 0.f, 0.f, 0.f};

  for (int c = 0; c < 4; ++c) {
    const int cb = c * 256;
    // GEMM1: h_chunk[16,256] = axs_tile[16,96] @ W1[:, cb..cb+255]
#pragma unroll 4
    for (int nt = 0; nt < 16; ++nt) {
      const int ng = cb + nt * 16 + tn;
      f4_t acc = {0.f, 0.f, 0.f, 0.f};
#pragma unroll
      for (int kc = 0; kc < 3; ++kc) {
        sh8 b = *(const sh8*)&w1t[(size_t)ng * XPAD + kc * 32 + quad * 8];
        acc = __builtin_amdgcn_mfma_f32_16x16x32_bf16(a1[kc], b, acc, 0, 0, 0);
      }
      float bias = b1s[ng];
#pragma unroll
      for (int r = 0; r < 4; ++r) {
        float v = relu_(acc[r] + bias);            // C: col=tn, row=quad*4+r
        hs[(m0 + quad * 4 + r) * 264 + nt * 16 + tn] = f2bf(v);
      }
    }
    // GEMM2: z[16,32] += h_chunk[16,256] @ W2[cb..cb+255, :]
#pragma unroll
    for (int kc = 0; kc < 8; ++kc) {
      sh8 a2 = *(const sh8*)&hs[(m0 + tn) * 264 + kc * 32 + quad * 8];
      sh8 bl = *(const sh8*)&w2t[(size_t)tn * DHID + cb + kc * 32 + quad * 8];
      z0 = __builtin_amdgcn_mfma_f32_16x16x32_bf16(a2, bl, z0, 0, 0, 0);
      sh8 bh = *(const sh8*)&w2t[(size_t)(16 + tn) * DHID + cb + kc * 32 + quad * 8];
      z1 = __builtin_amdgcn_mfma_f32_16x16x32_bf16(a2, bh, z1, 0, 0, 0);
    }
  }

#pragma unroll
  for (int r = 0; r < 4; ++r) {
    int node = n0 + m0 + quad * 4 + r;
    if (node < NN) {
      zb[(size_t)node * ZPAD + tn]      = f2bf(z0[r]);
      zb[(size_t)node * ZPAD + 16 + tn] = f2bf(z1[r]);
    }
  }
}

extern "C" void kernel_launch(void* const* d_in, const int* in_sizes, int n_in,
                              void* d_out, int out_size, void* d_ws, size_t ws_size,
                              hipStream_t stream) {
  const float* feature = (const float*)d_in[0];
  const float* conv_w  = (const float*)d_in[1];
  const float* conv_b  = (const float*)d_in[2];
  const float* W1      = (const float*)d_in[3];
  const float* b1      = (const float*)d_in[4];
  const float* W2      = (const float*)d_in[5];
  const float* b2      = (const float*)d_in[6];
  const float* adj     = (const float*)d_in[7];
  const int*   erow    = (const int*)d_in[8];
  const int*   ecol    = (const int*)d_in[9];
  float* out = (float*)d_out;

  char* B = (char*)d_ws;
  size_t o = 0;
  auto alloc = [&](size_t bytes, size_t align) -> void* {
    o = (o + align - 1) & ~(align - 1);
    void* p = B + o;
    o += bytes;
    return p;
  };
  unsigned short* x    = (unsigned short*)alloc((size_t)NN * XPAD * 2, 16);
  unsigned short* ax   = (unsigned short*)alloc((size_t)NN * XPAD * 2, 16);
  unsigned short* zb   = (unsigned short*)alloc((size_t)NN * ZPAD * 2, 16);
  int*   counts  = (int*)alloc((size_t)NN * 4, 16);
  int*   offs    = (int*)alloc((size_t)NN * 4, 16);
  int*   gcur    = (int*)alloc((size_t)NBK * 16 * 4, 64);  // line-padded cursors
  int*   partial = (int*)alloc(512 * 4, 16);
  int*   base    = (int*)alloc(512 * 4, 16);
  unsigned short* w1t = (unsigned short*)alloc((size_t)DHID * XPAD * 2, 16);
  unsigned short* w2t = (unsigned short*)alloc((size_t)32 * DHID * 2, 16);
  int2*  tmp     = (int2*)alloc((size_t)EE * 8, 16);  // bucket-major
  int2*  csr     = (int2*)alloc((size_t)EE * 8, 16);  // row-sorted

  // 1) x = relu(conv_sum(feature)) -> bf16 [NN][96]; weight prep
  conv_relu_k<<<8192, 256, 0, stream>>>(feature, conv_w, conv_b, x);
  w1t_k<<<(DHID * XPAD + 255) / 256, 256, 0, stream>>>(W1, w1t);
  w2t_k<<<(32 * DHID + 255) / 256, 256, 0, stream>>>(W2, w2t);
  // 2) CSR build: hist -> scan -> offsets(+bucket cursors) -> 2-level scatter
  zero_int_k<<<512, 256, 0, stream>>>(counts, NN);
  hist_k<<<8192, 256, 0, stream>>>(erow, counts);
  partial_k<<<NB_PART, 256, 0, stream>>>(counts, partial);
  scanpart_k<<<1, 512, 0, stream>>>(partial, base);
  offsets_k<<<NB_PART, 256, 0, stream>>>(counts, base, offs, gcur);
  partition_k<<<(EE + CHUNK - 1) / CHUNK, 256, 0, stream>>>(adj, erow, ecol, gcur, tmp);
  fine_scatter_k<<<NBK, 256, 0, stream>>>(offs, tmp, csr);
  // 3) ax = A @ x (gather, bf16 rows, ILP-8)
  spmm83_g<<<(NN + 3) / 4, 256, 0, stream>>>(offs, counts, csr, x, ax);
  // 4) z = relu(ax @ W1 + b1) @ W2 via bf16 MFMA -> bf16 [NN][32]
  fused_mlp_mfma<<<(NN + 63) / 64, 256, 0, stream>>>(ax, w1t, b1, w2t, zb);
  // 5) out = A @ z + b2 (gather, 1 line per edge, ILP-4)
  spmm25_g<<<(NN + 15) / 16, 256, 0, stream>>>(offs, counts, csr, zb, b2, out);
}

// Round 6
// 618.491 us; speedup vs baseline: 4.0939x; 1.0821x over previous
//
#include <hip/hip_runtime.h>

#define NN   100000
#define EE   3200000
#define DIN  83
#define DHID 1024
#define NCLS 25
#define XPAD 96    // x/ax bf16 row padding (192 B = 3 cache lines)
#define ZPAD 32    // z bf16 row padding (64 B = 1 cache line)

#define NB_PART 391   // ceil(NN/256)
#define NBK     391   // buckets of 256 rows (row >> 8)
#define CHUNK   8192  // edges per partition block

typedef __attribute__((__ext_vector_type__(8))) short sh8;
typedef __attribute__((__ext_vector_type__(4))) float f4_t;

static __device__ __forceinline__ float relu_(float v) { return v > 0.f ? v : 0.f; }

// f32 -> bf16 (RNE)
static __device__ __forceinline__ unsigned short f2bf(float f) {
  unsigned int u = __float_as_uint(f);
  unsigned int r = u + 0x7FFFu + ((u >> 16) & 1u);
  return (unsigned short)(r >> 16);
}
// packed bf16 pair -> two f32
static __device__ __forceinline__ float bflo(unsigned int q) {
  return __uint_as_float(q << 16);
}
static __device__ __forceinline__ float bfhi(unsigned int q) {
  return __uint_as_float(q & 0xFFFF0000u);
}

// K1: Conv1d(1->4,k5,p2) + channel-sum + bias + relu -> bf16 x[NN][96]
__global__ void conv_relu_k(const float* __restrict__ feature,
                            const float* __restrict__ conv_w,
                            const float* __restrict__ conv_b,
                            unsigned short* __restrict__ x) {
  float ws0 = conv_w[0] + conv_w[5] + conv_w[10] + conv_w[15];
  float ws1 = conv_w[1] + conv_w[6] + conv_w[11] + conv_w[16];
  float ws2 = conv_w[2] + conv_w[7] + conv_w[12] + conv_w[17];
  float ws3 = conv_w[3] + conv_w[8] + conv_w[13] + conv_w[18];
  float ws4 = conv_w[4] + conv_w[9] + conv_w[14] + conv_w[19];
  float bs  = conv_b[0] + conv_b[1] + conv_b[2] + conv_b[3];
  const int total = NN * XPAD;
  for (int idx = blockIdx.x * blockDim.x + threadIdx.x; idx < total;
       idx += gridDim.x * blockDim.x) {
    int n = idx / XPAD;
    int i = idx - n * XPAD;
    unsigned short o = 0;
    if (i < DIN) {
      const float* f = feature + (size_t)n * DIN;
      float acc = bs;
      if (i >= 2)      acc += ws0 * f[i - 2];
      if (i >= 1)      acc += ws1 * f[i - 1];
      acc += ws2 * f[i];
      if (i + 1 < DIN) acc += ws3 * f[i + 1];
      if (i + 2 < DIN) acc += ws4 * f[i + 2];
      o = f2bf(relu_(acc));
    }
    x[idx] = o;
  }
}

__global__ void zero_int_k(int* __restrict__ p, int total) {
  for (int i = blockIdx.x * blockDim.x + threadIdx.x; i < total;
       i += gridDim.x * blockDim.x)
    p[i] = 0;
}

// W1[83,1024] f32 -> w1t[1024][96] bf16 (transposed, K zero-padded)
__global__ void w1t_k(const float* __restrict__ W1, unsigned short* __restrict__ w1t) {
  int idx = blockIdx.x * blockDim.x + threadIdx.x;
  if (idx >= DHID * XPAD) return;
  int k = idx / DHID;
  int n = idx - k * DHID;
  float v = (k < DIN) ? W1[k * DHID + n] : 0.f;
  w1t[n * XPAD + k] = f2bf(v);
}

// W2[1024,25] f32 -> w2t[32][1024] bf16 (transposed, N zero-padded)
__global__ void w2t_k(const float* __restrict__ W2, unsigned short* __restrict__ w2t) {
  int idx = blockIdx.x * blockDim.x + threadIdx.x;
  if (idx >= 32 * DHID) return;
  int k = idx / 32;
  int n = idx - k * 32;
  float v = (n < NCLS) ? W2[k * NCLS + n] : 0.f;
  w2t[n * DHID + k] = f2bf(v);
}

// ---- CSR build ----
__global__ void hist_k(const int* __restrict__ row, int* __restrict__ counts) {
  for (int e = blockIdx.x * blockDim.x + threadIdx.x; e < EE;
       e += gridDim.x * blockDim.x)
    atomicAdd(&counts[row[e]], 1);
}

__global__ void partial_k(const int* __restrict__ counts, int* __restrict__ partial) {
  __shared__ int sd[256];
  int t = threadIdx.x;
  int i = blockIdx.x * 256 + t;
  sd[t] = (i < NN) ? counts[i] : 0;
  __syncthreads();
  for (int off = 128; off > 0; off >>= 1) {
    if (t < off) sd[t] += sd[t + off];
    __syncthreads();
  }
  if (t == 0) partial[blockIdx.x] = sd[0];
}

__global__ void scanpart_k(const int* __restrict__ partial, int* __restrict__ base) {
  __shared__ int sd[512];
  int t = threadIdx.x;
  int v = (t < NB_PART) ? partial[t] : 0;
  sd[t] = v;
  __syncthreads();
  for (int off = 1; off < 512; off <<= 1) {
    int add = (t >= off) ? sd[t - off] : 0;
    __syncthreads();
    sd[t] += add;
    __syncthreads();
  }
  if (t < NB_PART) base[t] = sd[t] - v;  // exclusive
}

// per-block scan -> offs; also seed bucket cursors gcur (line-padded, stride 16)
__global__ void offsets_k(const int* __restrict__ counts, const int* __restrict__ base,
                          int* __restrict__ offs, int* __restrict__ gcur) {
  __shared__ int sd[256];
  int t = threadIdx.x;
  int i = blockIdx.x * 256 + t;
  int v = (i < NN) ? counts[i] : 0;
  sd[t] = v;
  __syncthreads();
  for (int off = 1; off < 256; off <<= 1) {
    int add = (t >= off) ? sd[t - off] : 0;
    __syncthreads();
    sd[t] += add;
    __syncthreads();
  }
  if (i < NN) {
    int excl = sd[t] - v + base[blockIdx.x];
    offs[i] = excl;
    if ((i & 255) == 0) gcur[(i >> 8) * 16] = excl;  // bucket start cursor
  }
}

// Pass 1: partition edges into 391 buckets (row>>8), bucket-major tmp.
__global__ __launch_bounds__(256) void partition_k(
    const float* __restrict__ vals, const int* __restrict__ row,
    const int* __restrict__ col, int* __restrict__ gcur,
    int2* __restrict__ tmp) {
  __shared__ int cnt[NBK];
  __shared__ int sc[512];     // scan scratch
  __shared__ int es[NBK];     // exclusive start per bucket
  __shared__ int lcur[NBK];
  __shared__ int gbase[NBK];
  __shared__ int2 staged[CHUNK];
  const int tid = threadIdx.x;
  const int cb = blockIdx.x * CHUNK;
  const int csize = (cb + CHUNK <= EE) ? CHUNK : (EE - cb);

  for (int b = tid; b < NBK; b += 256) cnt[b] = 0;
  __syncthreads();
  for (int i = tid; i < csize; i += 256)
    atomicAdd(&cnt[row[cb + i] >> 8], 1);
  __syncthreads();
  sc[tid]       = (tid < NBK) ? cnt[tid] : 0;
  sc[tid + 256] = (tid + 256 < NBK) ? cnt[tid + 256] : 0;
  __syncthreads();
  for (int off = 1; off < 512; off <<= 1) {
    int a0 = (tid >= off) ? sc[tid - off] : 0;
    int a1 = (tid + 256 >= off) ? sc[tid + 256 - off] : 0;
    __syncthreads();
    sc[tid] += a0;
    sc[tid + 256] += a1;
    __syncthreads();
  }
  for (int b = tid; b < NBK; b += 256) {
    int e = sc[b] - cnt[b];   // exclusive
    es[b] = e;
    lcur[b] = e;
  }
  __syncthreads();
  for (int b = tid; b < NBK; b += 256)
    gbase[b] = cnt[b] ? atomicAdd(&gcur[b * 16], cnt[b]) : 0;
  __syncthreads();
  for (int i = tid; i < csize; i += 256) {
    int r = row[cb + i];
    int lpos = atomicAdd(&lcur[r >> 8], 1);
    staged[lpos] = make_int2(col[cb + i] | ((r & 255) << 17),
                             __float_as_int(vals[cb + i]));
  }
  __syncthreads();
  for (int j = tid; j < csize; j += 256) {
    int lo = 0, hi = NBK - 1;          // largest b with es[b] <= j
    while (lo < hi) {
      int mid = (lo + hi + 1) >> 1;
      if (es[mid] <= j) lo = mid; else hi = mid - 1;
    }
    tmp[gbase[lo] + (j - es[lo])] = staged[j];
  }
}

// Pass 2: per-bucket fine scatter (row cursors in LDS, writes CU/L2-local).
__global__ __launch_bounds__(256) void fine_scatter_k(
    const int* __restrict__ offs, const int2* __restrict__ tmp,
    int2* __restrict__ csr) {
  __shared__ int lcur[256];
  const int tid = threadIdx.x;
  const int b = blockIdx.x;
  const int r0 = b * 256;
  const int nr = (r0 + 256 <= NN) ? 256 : (NN - r0);
  if (tid < nr) lcur[tid] = offs[r0 + tid];   // absolute cursors
  __syncthreads();
  const int gstart = offs[r0];
  const int gend = (b == NBK - 1) ? EE : offs[r0 + 256];
  for (int i = tid; i < gend - gstart; i += 256) {
    int2 p = tmp[gstart + i];
    int rl = p.x >> 17;
    int pos = atomicAdd(&lcur[rl], 1);
    csr[pos] = make_int2(p.x & 0x1FFFF, p.y);
  }
}

// ---- gather SpMM, D=83(96 bf16): one wave per row, ILP-8 edge unroll ----
__global__ __launch_bounds__(256) void spmm83_g(
    const int* __restrict__ offs, const int* __restrict__ cnt,
    const int2* __restrict__ csr, const unsigned short* __restrict__ x,
    unsigned short* __restrict__ ax) {
  int wave = (int)((blockIdx.x * blockDim.x + threadIdx.x) >> 6);
  int lane = threadIdx.x & 63;
  if (wave >= NN) return;
  int s = offs[wave];
  int n = cnt[wave];
  const bool act = lane < 48;         // 48 lanes x short2 = 96 dims
  const int d2 = lane * 2;
  float a0 = 0.f, a1 = 0.f;
  int i = 0;
  for (; i + 8 <= n; i += 8) {
    int2 p[8];
#pragma unroll
    for (int u = 0; u < 8; ++u) p[u] = csr[s + i + u];
    if (act) {
      unsigned int q[8];
#pragma unroll
      for (int u = 0; u < 8; ++u)
        q[u] = *(const unsigned int*)&x[(size_t)p[u].x * XPAD + d2];
#pragma unroll
      for (int u = 0; u < 8; ++u) {
        float v = __int_as_float(p[u].y);
        a0 += v * bflo(q[u]);
        a1 += v * bfhi(q[u]);
      }
    }
  }
  for (; i < n; ++i) {
    int2 p = csr[s + i];
    if (act) {
      unsigned int q = *(const unsigned int*)&x[(size_t)p.x * XPAD + d2];
      float v = __int_as_float(p.y);
      a0 += v * bflo(q);
      a1 += v * bfhi(q);
    }
  }
  if (act) {
    unsigned int o = (unsigned int)f2bf(a0) | ((unsigned int)f2bf(a1) << 16);
    *(unsigned int*)&ax[(size_t)wave * XPAD + d2] = o;
  }
}

// ---- gather SpMM, D=25(32 bf16): 4 rows per wave (16 lanes each), ILP-4, +b2 ----
__global__ __launch_bounds__(256) void spmm25_g(
    const int* __restrict__ offs, const int* __restrict__ cnt,
    const int2* __restrict__ csr, const unsigned short* __restrict__ zb,
    const float* __restrict__ b2, float* __restrict__ out) {
  int gw = (int)((blockIdx.x * blockDim.x + threadIdx.x) >> 6);
  int lane = threadIdx.x & 63;
  int sub = lane >> 4;
  int d2 = (lane & 15) * 2;
  int r = gw * 4 + sub;
  if (r >= NN) return;
  int s = offs[r];
  int n = cnt[r];
  float a0 = 0.f, a1 = 0.f;
  int i = 0;
  for (; i + 4 <= n; i += 4) {
    int2 p0 = csr[s + i + 0];
    int2 p1 = csr[s + i + 1];
    int2 p2 = csr[s + i + 2];
    int2 p3 = csr[s + i + 3];
    unsigned int q0 = *(const unsigned int*)&zb[(size_t)p0.x * ZPAD + d2];
    unsigned int q1 = *(const unsigned int*)&zb[(size_t)p1.x * ZPAD + d2];
    unsigned int q2 = *(const unsigned int*)&zb[(size_t)p2.x * ZPAD + d2];
    unsigned int q3 = *(const unsigned int*)&zb[(size_t)p3.x * ZPAD + d2];
    float v0 = __int_as_float(p0.y), v1 = __int_as_float(p1.y);
    float v2 = __int_as_float(p2.y), v3 = __int_as_float(p3.y);
    a0 += v0 * bflo(q0) + v1 * bflo(q1) + v2 * bflo(q2) + v3 * bflo(q3);
    a1 += v0 * bfhi(q0) + v1 * bfhi(q1) + v2 * bfhi(q2) + v3 * bfhi(q3);
  }
  for (; i < n; ++i) {
    int2 p = csr[s + i];
    unsigned int q = *(const unsigned int*)&zb[(size_t)p.x * ZPAD + d2];
    float v = __int_as_float(p.y);
    a0 += v * bflo(q);
    a1 += v * bfhi(q);
  }
  if (d2 < NCLS)     out[(size_t)r * NCLS + d2]     = a0 + b2[d2];
  if (d2 + 1 < NCLS) out[(size_t)r * NCLS + d2 + 1] = a1 + b2[d2 + 1];
}

// ---- Fused MLP via bf16 MFMA: z = relu(ax@W1+b1)@W2, z -> bf16[NN][32] ----
// Block = 64 nodes, 4 waves. GEMM1: wave holds A-frags for ALL 4 m-tiles
// (48 VGPRs) and covers n-tiles w*4..w*4+3 -> each B-frag load feeds 4 MFMAs.
// GEMM2: wave owns m-tile w. 2 barriers per 256-chunk (hs cross-wave).
__global__ __launch_bounds__(256) void fused_mlp_mfma(
    const unsigned short* __restrict__ axg, const unsigned short* __restrict__ w1t,
    const float* __restrict__ b1, const unsigned short* __restrict__ w2t,
    unsigned short* __restrict__ zb) {
  __shared__ __align__(16) unsigned short axs[64 * 104];  // [64][96] pad->104
  __shared__ __align__(16) unsigned short hs[64 * 264];   // [64][256] pad->264
  __shared__ float b1s[DHID];
  const int tid = threadIdx.x;
  const int n0 = blockIdx.x * 64;

  for (int idx = tid; idx < 64 * 12; idx += 256) {   // 12 sh8 chunks per row
    int m = idx / 12;
    int c8 = idx - m * 12;
    int node = n0 + m;
    sh8 v = {0, 0, 0, 0, 0, 0, 0, 0};
    if (node < NN) v = *(const sh8*)&axg[(size_t)node * XPAD + c8 * 8];
    *(sh8*)&axs[m * 104 + c8 * 8] = v;
  }
  for (int i = tid; i < DHID; i += 256) b1s[i] = b1[i];
  __syncthreads();

  const int lane = tid & 63;
  const int w = tid >> 6;
  const int quad = lane >> 4;   // A/B frag: k = quad*8 + j
  const int tn = lane & 15;     // A frag: m; B frag: n; C frag: col
  const int m0 = w * 16;

  // A-frags for all four m-tiles, resident across the whole hidden dim
  sh8 a1[4][3];
#pragma unroll
  for (int mt = 0; mt < 4; ++mt)
#pragma unroll
    for (int kc = 0; kc < 3; ++kc)
      a1[mt][kc] = *(const sh8*)&axs[(mt * 16 + tn) * 104 + kc * 32 + quad * 8];

  f4_t z0 = {0.f, 0.f, 0.f, 0.f}, z1 = {0.f, 0.f, 0.f, 0.f};

  for (int c = 0; c < 4; ++c) {
    const int cb = c * 256;
    // GEMM1 (cooperative): wave w -> n-tiles w*4..w*4+3, all 4 m-tiles
#pragma unroll
    for (int nti = 0; nti < 4; ++nti) {
      const int nt = w * 4 + nti;
      const int ng = cb + nt * 16 + tn;
      const unsigned short* wr = &w1t[(size_t)ng * XPAD + quad * 8];
      sh8 b0 = *(const sh8*)&wr[0];
      sh8 b1f = *(const sh8*)&wr[32];
      sh8 b2f = *(const sh8*)&wr[64];
      float bias = b1s[ng];
#pragma unroll
      for (int mt = 0; mt < 4; ++mt) {
        f4_t acc = {0.f, 0.f, 0.f, 0.f};
        acc = __builtin_amdgcn_mfma_f32_16x16x32_bf16(a1[mt][0], b0, acc, 0, 0, 0);
        acc = __builtin_amdgcn_mfma_f32_16x16x32_bf16(a1[mt][1], b1f, acc, 0, 0, 0);
        acc = __builtin_amdgcn_mfma_f32_16x16x32_bf16(a1[mt][2], b2f, acc, 0, 0, 0);
#pragma unroll
        for (int r = 0; r < 4; ++r) {
          float v = relu_(acc[r] + bias);          // C: col=tn, row=quad*4+r
          hs[(mt * 16 + quad * 4 + r) * 264 + nt * 16 + tn] = f2bf(v);
        }
      }
    }
    __syncthreads();
    // GEMM2: z[16,32] += h_chunk[16,256] @ W2[cb..cb+255, :]; wave w -> m-tile w
#pragma unroll
    for (int kc = 0; kc < 8; ++kc) {
      sh8 a2 = *(const sh8*)&hs[(m0 + tn) * 264 + kc * 32 + quad * 8];
      sh8 bl = *(const sh8*)&w2t[(size_t)tn * DHID + cb + kc * 32 + quad * 8];
      z0 = __builtin_amdgcn_mfma_f32_16x16x32_bf16(a2, bl, z0, 0, 0, 0);
      sh8 bh = *(const sh8*)&w2t[(size_t)(16 + tn) * DHID + cb + kc * 32 + quad * 8];
      z1 = __builtin_amdgcn_mfma_f32_16x16x32_bf16(a2, bh, z1, 0, 0, 0);
    }
    __syncthreads();
  }

#pragma unroll
  for (int r = 0; r < 4; ++r) {
    int node = n0 + m0 + quad * 4 + r;
    if (node < NN) {
      zb[(size_t)node * ZPAD + tn]      = f2bf(z0[r]);
      zb[(size_t)node * ZPAD + 16 + tn] = f2bf(z1[r]);
    }
  }
}

extern "C" void kernel_launch(void* const* d_in, const int* in_sizes, int n_in,
                              void* d_out, int out_size, void* d_ws, size_t ws_size,
                              hipStream_t stream) {
  const float* feature = (const float*)d_in[0];
  const float* conv_w  = (const float*)d_in[1];
  const float* conv_b  = (const float*)d_in[2];
  const float* W1      = (const float*)d_in[3];
  const float* b1      = (const float*)d_in[4];
  const float* W2      = (const float*)d_in[5];
  const float* b2      = (const float*)d_in[6];
  const float* adj     = (const float*)d_in[7];
  const int*   erow    = (const int*)d_in[8];
  const int*   ecol    = (const int*)d_in[9];
  float* out = (float*)d_out;

  char* B = (char*)d_ws;
  size_t o = 0;
  auto alloc = [&](size_t bytes, size_t align) -> void* {
    o = (o + align - 1) & ~(align - 1);
    void* p = B + o;
    o += bytes;
    return p;
  };
  unsigned short* x    = (unsigned short*)alloc((size_t)NN * XPAD * 2, 16);
  unsigned short* ax   = (unsigned short*)alloc((size_t)NN * XPAD * 2, 16);
  unsigned short* zb   = (unsigned short*)alloc((size_t)NN * ZPAD * 2, 16);
  int*   counts  = (int*)alloc((size_t)NN * 4, 16);
  int*   offs    = (int*)alloc((size_t)NN * 4, 16);
  int*   gcur    = (int*)alloc((size_t)NBK * 16 * 4, 64);  // line-padded cursors
  int*   partial = (int*)alloc(512 * 4, 16);
  int*   base    = (int*)alloc(512 * 4, 16);
  unsigned short* w1t = (unsigned short*)alloc((size_t)DHID * XPAD * 2, 16);
  unsigned short* w2t = (unsigned short*)alloc((size_t)32 * DHID * 2, 16);
  int2*  tmp     = (int2*)alloc((size_t)EE * 8, 16);  // bucket-major
  int2*  csr     = (int2*)alloc((size_t)EE * 8, 16);  // row-sorted

  // 1) x = relu(conv_sum(feature)) -> bf16 [NN][96]; weight prep
  conv_relu_k<<<8192, 256, 0, stream>>>(feature, conv_w, conv_b, x);
  w1t_k<<<(DHID * XPAD + 255) / 256, 256, 0, stream>>>(W1, w1t);
  w2t_k<<<(32 * DHID + 255) / 256, 256, 0, stream>>>(W2, w2t);
  // 2) CSR build: hist -> scan -> offsets(+bucket cursors) -> 2-level scatter
  zero_int_k<<<512, 256, 0, stream>>>(counts, NN);
  hist_k<<<8192, 256, 0, stream>>>(erow, counts);
  partial_k<<<NB_PART, 256, 0, stream>>>(counts, partial);
  scanpart_k<<<1, 512, 0, stream>>>(partial, base);
  offsets_k<<<NB_PART, 256, 0, stream>>>(counts, base, offs, gcur);
  partition_k<<<(EE + CHUNK - 1) / CHUNK, 256, 0, stream>>>(adj, erow, ecol, gcur, tmp);
  fine_scatter_k<<<NBK, 256, 0, stream>>>(offs, tmp, csr);
  // 3) ax = A @ x (gather, bf16 rows, ILP-8)
  spmm83_g<<<(NN + 3) / 4, 256, 0, stream>>>(offs, counts, csr, x, ax);
  // 4) z = relu(ax @ W1 + b1) @ W2 via bf16 MFMA -> bf16 [NN][32]
  fused_mlp_mfma<<<(NN + 63) / 64, 256, 0, stream>>>(ax, w1t, b1, w2t, zb);
  // 5) out = A @ z + b2 (gather, 1 line per edge, ILP-4)
  spmm25_g<<<(NN + 15) / 16, 256, 0, stream>>>(offs, counts, csr, zb, b2, out);
}

// Round 7
// 505.414 us; speedup vs baseline: 5.0098x; 1.2237x over previous
//
#include <hip/hip_runtime.h>

#define NN   100000
#define EE   3200000
#define DIN  83
#define DHID 1024
#define NCLS 25
#define XPAD 96    // x/ax bf16 row padding (192 B = 3 cache lines)
#define ZPAD 32    // z bf16 row padding (64 B = 1 cache line)

#define NBK     391   // buckets of 256 rows (row >> 8)
#define CHUNK   8192  // edges per partition block

typedef __attribute__((__ext_vector_type__(8))) short sh8;
typedef __attribute__((__ext_vector_type__(4))) float f4_t;

static __device__ __forceinline__ float relu_(float v) { return v > 0.f ? v : 0.f; }

// f32 -> bf16 (RNE)
static __device__ __forceinline__ unsigned short f2bf(float f) {
  unsigned int u = __float_as_uint(f);
  unsigned int r = u + 0x7FFFu + ((u >> 16) & 1u);
  return (unsigned short)(r >> 16);
}
// packed bf16 pair -> two f32
static __device__ __forceinline__ float bflo(unsigned int q) {
  return __uint_as_float(q << 16);
}
static __device__ __forceinline__ float bfhi(unsigned int q) {
  return __uint_as_float(q & 0xFFFF0000u);
}

// K1: Conv1d(1->4,k5,p2) + channel-sum + bias + relu -> bf16 x[NN][96]
__global__ void conv_relu_k(const float* __restrict__ feature,
                            const float* __restrict__ conv_w,
                            const float* __restrict__ conv_b,
                            unsigned short* __restrict__ x) {
  float ws0 = conv_w[0] + conv_w[5] + conv_w[10] + conv_w[15];
  float ws1 = conv_w[1] + conv_w[6] + conv_w[11] + conv_w[16];
  float ws2 = conv_w[2] + conv_w[7] + conv_w[12] + conv_w[17];
  float ws3 = conv_w[3] + conv_w[8] + conv_w[13] + conv_w[18];
  float ws4 = conv_w[4] + conv_w[9] + conv_w[14] + conv_w[19];
  float bs  = conv_b[0] + conv_b[1] + conv_b[2] + conv_b[3];
  const int total = NN * XPAD;
  for (int idx = blockIdx.x * blockDim.x + threadIdx.x; idx < total;
       idx += gridDim.x * blockDim.x) {
    int n = idx / XPAD;
    int i = idx - n * XPAD;
    unsigned short o = 0;
    if (i < DIN) {
      const float* f = feature + (size_t)n * DIN;
      float acc = bs;
      if (i >= 2)      acc += ws0 * f[i - 2];
      if (i >= 1)      acc += ws1 * f[i - 1];
      acc += ws2 * f[i];
      if (i + 1 < DIN) acc += ws3 * f[i + 1];
      if (i + 2 < DIN) acc += ws4 * f[i + 2];
      o = f2bf(relu_(acc));
    }
    x[idx] = o;
  }
}

__global__ void zero_int_k(int* __restrict__ p, int total) {
  for (int i = blockIdx.x * blockDim.x + threadIdx.x; i < total;
       i += gridDim.x * blockDim.x)
    p[i] = 0;
}

// W1[83,1024] f32 -> w1t[1024][96] bf16 (transposed, K zero-padded)
__global__ void w1t_k(const float* __restrict__ W1, unsigned short* __restrict__ w1t) {
  int idx = blockIdx.x * blockDim.x + threadIdx.x;
  if (idx >= DHID * XPAD) return;
  int k = idx / DHID;
  int n = idx - k * DHID;
  float v = (k < DIN) ? W1[k * DHID + n] : 0.f;
  w1t[n * XPAD + k] = f2bf(v);
}

// W2[1024,25] f32 -> w2t[32][1024] bf16 (transposed, N zero-padded)
__global__ void w2t_k(const float* __restrict__ W2, unsigned short* __restrict__ w2t) {
  int idx = blockIdx.x * blockDim.x + threadIdx.x;
  if (idx >= 32 * DHID) return;
  int k = idx / 32;
  int n = idx - k * 32;
  float v = (n < NCLS) ? W2[k * NCLS + n] : 0.f;
  w2t[n * DHID + k] = f2bf(v);
}

// ---- CSR build (bucket-hierarchical, no global per-row histogram) ----

// Per-block LDS histogram over 391 buckets; one global atomic per bucket/block.
__global__ __launch_bounds__(256) void bucket_hist_k(
    const int* __restrict__ row, int* __restrict__ gbk) {
  __shared__ int cnt[NBK];
  const int tid = threadIdx.x;
  for (int b = tid; b < NBK; b += 256) cnt[b] = 0;
  __syncthreads();
  const int cb = blockIdx.x * CHUNK;
  const int csize = (cb + CHUNK <= EE) ? CHUNK : (EE - cb);
  for (int i = tid; i < csize; i += 256)
    atomicAdd(&cnt[row[cb + i] >> 8], 1);
  __syncthreads();
  for (int b = tid; b < NBK; b += 256)
    if (cnt[b]) atomicAdd(&gbk[b], cnt[b]);
}

// Single-block scan of bucket totals -> bucket bases (+ seed partition cursors)
__global__ void scan_buckets_k(const int* __restrict__ gbk,
                               int* __restrict__ bbase, int* __restrict__ gcur) {
  __shared__ int sd[512];
  int t = threadIdx.x;
  int v = (t < NBK) ? gbk[t] : 0;
  sd[t] = v;
  __syncthreads();
  for (int off = 1; off < 512; off <<= 1) {
    int add = (t >= off) ? sd[t - off] : 0;
    __syncthreads();
    sd[t] += add;
    __syncthreads();
  }
  if (t < NBK) {
    int excl = sd[t] - v;
    bbase[t] = excl;
    gcur[t * 16] = excl;   // line-padded cursor
  }
  if (t == 0) bbase[NBK] = EE;
}

// Pass 1: partition edges into 391 buckets (row>>8), bucket-major tmp.
__global__ __launch_bounds__(256) void partition_k(
    const float* __restrict__ vals, const int* __restrict__ row,
    const int* __restrict__ col, int* __restrict__ gcur,
    int2* __restrict__ tmp) {
  __shared__ int cnt[NBK];
  __shared__ int sc[512];     // scan scratch
  __shared__ int es[NBK];     // exclusive start per bucket
  __shared__ int lcur[NBK];
  __shared__ int gbase[NBK];
  __shared__ int2 staged[CHUNK];
  const int tid = threadIdx.x;
  const int cb = blockIdx.x * CHUNK;
  const int csize = (cb + CHUNK <= EE) ? CHUNK : (EE - cb);

  for (int b = tid; b < NBK; b += 256) cnt[b] = 0;
  __syncthreads();
  for (int i = tid; i < csize; i += 256)
    atomicAdd(&cnt[row[cb + i] >> 8], 1);
  __syncthreads();
  sc[tid]       = (tid < NBK) ? cnt[tid] : 0;
  sc[tid + 256] = (tid + 256 < NBK) ? cnt[tid + 256] : 0;
  __syncthreads();
  for (int off = 1; off < 512; off <<= 1) {
    int a0 = (tid >= off) ? sc[tid - off] : 0;
    int a1 = (tid + 256 >= off) ? sc[tid + 256 - off] : 0;
    __syncthreads();
    sc[tid] += a0;
    sc[tid + 256] += a1;
    __syncthreads();
  }
  for (int b = tid; b < NBK; b += 256) {
    int e = sc[b] - cnt[b];   // exclusive
    es[b] = e;
    lcur[b] = e;
  }
  __syncthreads();
  for (int b = tid; b < NBK; b += 256)
    gbase[b] = cnt[b] ? atomicAdd(&gcur[b * 16], cnt[b]) : 0;
  __syncthreads();
  for (int i = tid; i < csize; i += 256) {
    int r = row[cb + i];
    int lpos = atomicAdd(&lcur[r >> 8], 1);
    staged[lpos] = make_int2(col[cb + i] | ((r & 255) << 17),
                             __float_as_int(vals[cb + i]));
  }
  __syncthreads();
  for (int j = tid; j < csize; j += 256) {
    int lo = 0, hi = NBK - 1;          // largest b with es[b] <= j
    while (lo < hi) {
      int mid = (lo + hi + 1) >> 1;
      if (es[mid] <= j) lo = mid; else hi = mid - 1;
    }
    tmp[gbase[lo] + (j - es[lo])] = staged[j];
  }
}

// Pass 2: per-bucket fine scatter + per-row offset derivation (all in LDS).
__global__ __launch_bounds__(256) void fine_scatter2_k(
    const int* __restrict__ bbase, const int2* __restrict__ tmp,
    int2* __restrict__ csr, int* __restrict__ offs, int* __restrict__ counts) {
  __shared__ int cnt[256];
  __shared__ int sd[256];
  __shared__ int lcur[256];
  const int tid = threadIdx.x;
  const int b = blockIdx.x;
  const int r0 = b * 256;
  const int gstart = bbase[b];
  const int nedge = bbase[b + 1] - gstart;
  cnt[tid] = 0;
  __syncthreads();
  // Phase A: per-row histogram of this bucket's edges (LDS atomics)
  for (int i = tid; i < nedge; i += 256)
    atomicAdd(&cnt[((unsigned)tmp[gstart + i].x) >> 17], 1);
  __syncthreads();
  // Phase B: exclusive scan of 256 row counts -> per-row offsets
  int v = cnt[tid];
  sd[tid] = v;
  __syncthreads();
  for (int off = 1; off < 256; off <<= 1) {
    int add = (tid >= off) ? sd[tid - off] : 0;
    __syncthreads();
    sd[tid] += add;
    __syncthreads();
  }
  int excl = gstart + sd[tid] - v;
  int r = r0 + tid;
  if (r < NN) {
    offs[r] = excl;
    counts[r] = v;
  }
  lcur[tid] = excl;
  __syncthreads();
  // Phase C: scatter within the bucket's ~128KB window (L2-local)
  for (int i = tid; i < nedge; i += 256) {
    int2 p = tmp[gstart + i];
    int rl = ((unsigned)p.x) >> 17;
    int pos = atomicAdd(&lcur[rl], 1);
    csr[pos] = make_int2(p.x & 0x1FFFF, p.y);
  }
}

// ---- gather SpMM, D=83(96 bf16): one wave per row, ILP-8 edge unroll ----
__global__ __launch_bounds__(256) void spmm83_g(
    const int* __restrict__ offs, const int* __restrict__ cnt,
    const int2* __restrict__ csr, const unsigned short* __restrict__ x,
    unsigned short* __restrict__ ax) {
  int wave = (int)((blockIdx.x * blockDim.x + threadIdx.x) >> 6);
  int lane = threadIdx.x & 63;
  if (wave >= NN) return;
  int s = offs[wave];
  int n = cnt[wave];
  const bool act = lane < 48;         // 48 lanes x short2 = 96 dims
  const int d2 = lane * 2;
  float a0 = 0.f, a1 = 0.f;
  int i = 0;
  for (; i + 8 <= n; i += 8) {
    int2 p[8];
#pragma unroll
    for (int u = 0; u < 8; ++u) p[u] = csr[s + i + u];
    if (act) {
      unsigned int q[8];
#pragma unroll
      for (int u = 0; u < 8; ++u)
        q[u] = *(const unsigned int*)&x[(size_t)p[u].x * XPAD + d2];
#pragma unroll
      for (int u = 0; u < 8; ++u) {
        float v = __int_as_float(p[u].y);
        a0 += v * bflo(q[u]);
        a1 += v * bfhi(q[u]);
      }
    }
  }
  for (; i < n; ++i) {
    int2 p = csr[s + i];
    if (act) {
      unsigned int q = *(const unsigned int*)&x[(size_t)p.x * XPAD + d2];
      float v = __int_as_float(p.y);
      a0 += v * bflo(q);
      a1 += v * bfhi(q);
    }
  }
  if (act) {
    unsigned int o = (unsigned int)f2bf(a0) | ((unsigned int)f2bf(a1) << 16);
    *(unsigned int*)&ax[(size_t)wave * XPAD + d2] = o;
  }
}

// ---- gather SpMM, D=25(32 bf16): 4 rows per wave (16 lanes each), ILP-4, +b2 ----
__global__ __launch_bounds__(256) void spmm25_g(
    const int* __restrict__ offs, const int* __restrict__ cnt,
    const int2* __restrict__ csr, const unsigned short* __restrict__ zb,
    const float* __restrict__ b2, float* __restrict__ out) {
  int gw = (int)((blockIdx.x * blockDim.x + threadIdx.x) >> 6);
  int lane = threadIdx.x & 63;
  int sub = lane >> 4;
  int d2 = (lane & 15) * 2;
  int r = gw * 4 + sub;
  if (r >= NN) return;
  int s = offs[r];
  int n = cnt[r];
  float a0 = 0.f, a1 = 0.f;
  int i = 0;
  for (; i + 4 <= n; i += 4) {
    int2 p0 = csr[s + i + 0];
    int2 p1 = csr[s + i + 1];
    int2 p2 = csr[s + i + 2];
    int2 p3 = csr[s + i + 3];
    unsigned int q0 = *(const unsigned int*)&zb[(size_t)p0.x * ZPAD + d2];
    unsigned int q1 = *(const unsigned int*)&zb[(size_t)p1.x * ZPAD + d2];
    unsigned int q2 = *(const unsigned int*)&zb[(size_t)p2.x * ZPAD + d2];
    unsigned int q3 = *(const unsigned int*)&zb[(size_t)p3.x * ZPAD + d2];
    float v0 = __int_as_float(p0.y), v1 = __int_as_float(p1.y);
    float v2 = __int_as_float(p2.y), v3 = __int_as_float(p3.y);
    a0 += v0 * bflo(q0) + v1 * bflo(q1) + v2 * bflo(q2) + v3 * bflo(q3);
    a1 += v0 * bfhi(q0) + v1 * bfhi(q1) + v2 * bfhi(q2) + v3 * bfhi(q3);
  }
  for (; i < n; ++i) {
    int2 p = csr[s + i];
    unsigned int q = *(const unsigned int*)&zb[(size_t)p.x * ZPAD + d2];
    float v = __int_as_float(p.y);
    a0 += v * bflo(q);
    a1 += v * bfhi(q);
  }
  if (d2 < NCLS)     out[(size_t)r * NCLS + d2]     = a0 + b2[d2];
  if (d2 + 1 < NCLS) out[(size_t)r * NCLS + d2 + 1] = a1 + b2[d2 + 1];
}

// ---- Fused MLP via bf16 MFMA: z = relu(ax@W1+b1)@W2, z -> bf16[NN][32] ----
// Block = 64 nodes, 4 waves. GEMM1: wave holds A-frags for ALL 4 m-tiles and
// covers n-tiles w*4..w*4+3 -> each B-frag load feeds 4 MFMAs.
__global__ __launch_bounds__(256) void fused_mlp_mfma(
    const unsigned short* __restrict__ axg, const unsigned short* __restrict__ w1t,
    const float* __restrict__ b1, const unsigned short* __restrict__ w2t,
    unsigned short* __restrict__ zb) {
  __shared__ __align__(16) unsigned short axs[64 * 104];  // [64][96] pad->104
  __shared__ __align__(16) unsigned short hs[64 * 264];   // [64][256] pad->264
  __shared__ float b1s[DHID];
  const int tid = threadIdx.x;
  const int n0 = blockIdx.x * 64;

  for (int idx = tid; idx < 64 * 12; idx += 256) {   // 12 sh8 chunks per row
    int m = idx / 12;
    int c8 = idx - m * 12;
    int node = n0 + m;
    sh8 v = {0, 0, 0, 0, 0, 0, 0, 0};
    if (node < NN) v = *(const sh8*)&axg[(size_t)node * XPAD + c8 * 8];
    *(sh8*)&axs[m * 104 + c8 * 8] = v;
  }
  for (int i = tid; i < DHID; i += 256) b1s[i] = b1[i];
  __syncthreads();

  const int lane = tid & 63;
  const int w = tid >> 6;
  const int quad = lane >> 4;   // A/B frag: k = quad*8 + j
  const int tn = lane & 15;     // A frag: m; B frag: n; C frag: col
  const int m0 = w * 16;

  sh8 a1[4][3];
#pragma unroll
  for (int mt = 0; mt < 4; ++mt)
#pragma unroll
    for (int kc = 0; kc < 3; ++kc)
      a1[mt][kc] = *(const sh8*)&axs[(mt * 16 + tn) * 104 + kc * 32 + quad * 8];

  f4_t z0 = {0.f, 0.f, 0.f, 0.f}, z1 = {0.f, 0.f, 0.f, 0.f};

  for (int c = 0; c < 4; ++c) {
    const int cb = c * 256;
#pragma unroll
    for (int nti = 0; nti < 4; ++nti) {
      const int nt = w * 4 + nti;
      const int ng = cb + nt * 16 + tn;
      const unsigned short* wr = &w1t[(size_t)ng * XPAD + quad * 8];
      sh8 b0 = *(const sh8*)&wr[0];
      sh8 b1f = *(const sh8*)&wr[32];
      sh8 b2f = *(const sh8*)&wr[64];
      float bias = b1s[ng];
#pragma unroll
      for (int mt = 0; mt < 4; ++mt) {
        f4_t acc = {0.f, 0.f, 0.f, 0.f};
        acc = __builtin_amdgcn_mfma_f32_16x16x32_bf16(a1[mt][0], b0, acc, 0, 0, 0);
        acc = __builtin_amdgcn_mfma_f32_16x16x32_bf16(a1[mt][1], b1f, acc, 0, 0, 0);
        acc = __builtin_amdgcn_mfma_f32_16x16x32_bf16(a1[mt][2], b2f, acc, 0, 0, 0);
#pragma unroll
        for (int r = 0; r < 4; ++r) {
          float v = relu_(acc[r] + bias);          // C: col=tn, row=quad*4+r
          hs[(mt * 16 + quad * 4 + r) * 264 + nt * 16 + tn] = f2bf(v);
        }
      }
    }
    __syncthreads();
#pragma unroll
    for (int kc = 0; kc < 8; ++kc) {
      sh8 a2 = *(const sh8*)&hs[(m0 + tn) * 264 + kc * 32 + quad * 8];
      sh8 bl = *(const sh8*)&w2t[(size_t)tn * DHID + cb + kc * 32 + quad * 8];
      z0 = __builtin_amdgcn_mfma_f32_16x16x32_bf16(a2, bl, z0, 0, 0, 0);
      sh8 bh = *(const sh8*)&w2t[(size_t)(16 + tn) * DHID + cb + kc * 32 + quad * 8];
      z1 = __builtin_amdgcn_mfma_f32_16x16x32_bf16(a2, bh, z1, 0, 0, 0);
    }
    __syncthreads();
  }

#pragma unroll
  for (int r = 0; r < 4; ++r) {
    int node = n0 + m0 + quad * 4 + r;
    if (node < NN) {
      zb[(size_t)node * ZPAD + tn]      = f2bf(z0[r]);
      zb[(size_t)node * ZPAD + 16 + tn] = f2bf(z1[r]);
    }
  }
}

extern "C" void kernel_launch(void* const* d_in, const int* in_sizes, int n_in,
                              void* d_out, int out_size, void* d_ws, size_t ws_size,
                              hipStream_t stream) {
  const float* feature = (const float*)d_in[0];
  const float* conv_w  = (const float*)d_in[1];
  const float* conv_b  = (const float*)d_in[2];
  const float* W1      = (const float*)d_in[3];
  const float* b1      = (const float*)d_in[4];
  const float* W2      = (const float*)d_in[5];
  const float* b2      = (const float*)d_in[6];
  const float* adj     = (const float*)d_in[7];
  const int*   erow    = (const int*)d_in[8];
  const int*   ecol    = (const int*)d_in[9];
  float* out = (float*)d_out;

  char* B = (char*)d_ws;
  size_t o = 0;
  auto alloc = [&](size_t bytes, size_t align) -> void* {
    o = (o + align - 1) & ~(align - 1);
    void* p = B + o;
    o += bytes;
    return p;
  };
  unsigned short* x    = (unsigned short*)alloc((size_t)NN * XPAD * 2, 16);
  unsigned short* ax   = (unsigned short*)alloc((size_t)NN * XPAD * 2, 16);
  unsigned short* zb   = (unsigned short*)alloc((size_t)NN * ZPAD * 2, 16);
  int*   counts  = (int*)alloc((size_t)NN * 4, 16);
  int*   offs    = (int*)alloc((size_t)NN * 4, 16);
  int*   gcur    = (int*)alloc((size_t)NBK * 16 * 4, 64);  // line-padded cursors
  int*   gbk     = (int*)alloc((size_t)NBK * 4, 16);       // bucket totals
  int*   bbase   = (int*)alloc((size_t)(NBK + 1) * 4, 16); // bucket bases
  unsigned short* w1t = (unsigned short*)alloc((size_t)DHID * XPAD * 2, 16);
  unsigned short* w2t = (unsigned short*)alloc((size_t)32 * DHID * 2, 16);
  int2*  tmp     = (int2*)alloc((size_t)EE * 8, 16);  // bucket-major
  int2*  csr     = (int2*)alloc((size_t)EE * 8, 16);  // row-sorted

  // 1) x = relu(conv_sum(feature)) -> bf16 [NN][96]; weight prep
  conv_relu_k<<<8192, 256, 0, stream>>>(feature, conv_w, conv_b, x);
  w1t_k<<<(DHID * XPAD + 255) / 256, 256, 0, stream>>>(W1, w1t);
  w2t_k<<<(32 * DHID + 255) / 256, 256, 0, stream>>>(W2, w2t);
  // 2) CSR build: bucket hist -> bucket scan -> partition -> fine scatter(+offs)
  zero_int_k<<<2, 256, 0, stream>>>(gbk, NBK);
  bucket_hist_k<<<(EE + CHUNK - 1) / CHUNK, 256, 0, stream>>>(erow, gbk);
  scan_buckets_k<<<1, 512, 0, stream>>>(gbk, bbase, gcur);
  partition_k<<<(EE + CHUNK - 1) / CHUNK, 256, 0, stream>>>(adj, erow, ecol, gcur, tmp);
  fine_scatter2_k<<<NBK, 256, 0, stream>>>(bbase, tmp, csr, offs, counts);
  // 3) ax = A @ x (gather, bf16 rows, ILP-8)
  spmm83_g<<<(NN + 3) / 4, 256, 0, stream>>>(offs, counts, csr, x, ax);
  // 4) z = relu(ax @ W1 + b1) @ W2 via bf16 MFMA -> bf16 [NN][32]
  fused_mlp_mfma<<<(NN + 63) / 64, 256, 0, stream>>>(ax, w1t, b1, w2t, zb);
  // 5) out = A @ z + b2 (gather, 1 line per edge, ILP-4)
  spmm25_g<<<(NN + 15) / 16, 256, 0, stream>>>(offs, counts, csr, zb, b2, out);
}